// Round 2
// baseline (877.312 us; speedup 1.0000x reference)
//
#include <hip/hip_runtime.h>

typedef unsigned short u16;
typedef unsigned int u32;

__device__ __forceinline__ float bf2f(u16 u) {
    return __uint_as_float(((u32)u) << 16);
}
__device__ __forceinline__ u16 f2bf(float f) {
    u32 u = __float_as_uint(f);
    u32 r = (u + 0x7fffu + ((u >> 16) & 1u)) >> 16;
    return (u16)r;
}
// read element i of a tensor that is f32 (isf32!=0) or bf16 (isf32==0)
__device__ __forceinline__ float ldf(const void* p, int i, int isf32) {
    return isf32 ? ((const float*)p)[i] : bf2f(((const u16*)p)[i]);
}

// ---- canonical f32 param block offsets (in floats) ----
#define P_W1   0        // 128x64
#define P_W2   8192     // 64x64
#define P_B1   12288    // 64
#define P_B2   12352    // 64
#define P_A1W  12416    // 144
#define P_A1B  12560    // 1
#define P_T1W  12561    // 16
#define P_T1B  12577    // 16
#define P_A2W  12593    // 144
#define P_A2B  12737    // 1
#define P_T2W  12738    // 16
#define P_T2B  12754    // 16
#define P_CLSW 12770    // 128 (64x2)
#define P_CLSB 12898    // 2
#define P_TOT  12900

// ---------------------------------------------------------------------------
// Detect whether float tensors are f32 or bf16.
// bf16 N(0,1) data: bf16-exponent of either half is ~0x7F, never >=0xF0.
// f32 data: low u16 is uniform mantissa bits -> exponent field uniform ->
// >=0xF0 with p~6%/word. 4096 words => detection is certain (p_miss ~ e^-265).
// flag = 1 -> f32, 0 -> bf16. Deterministic given fixed inputs.
// ---------------------------------------------------------------------------
__global__ __launch_bounds__(256) void detect_dtype(
    const u32* __restrict__ xw, int nwords, int* __restrict__ flag)
{
    __shared__ int sbad;
    if (threadIdx.x == 0) sbad = 0;
    __syncthreads();
    int bad = 0;
    for (int i = threadIdx.x; i < nwords; i += 256) {
        u32 w = xw[i];
        int ea = (w >> 7) & 0xff;   // bf16 exponent of the LOW half
        if (ea >= 0xF0) bad = 1;
    }
    if (bad) sbad = 1;   // benign race, all writers write 1
    __syncthreads();
    if (threadIdx.x == 0) flag[0] = sbad;
}

// ---------------------------------------------------------------------------
// Convert all small parameter tensors into one f32 param block.
// ---------------------------------------------------------------------------
__global__ __launch_bounds__(256) void prep_params(
    const void* l1w, const void* l1b, const void* a1w, const void* a1b,
    const void* t1w, const void* t1b, const void* l2w, const void* l2b,
    const void* a2w, const void* a2b, const void* t2w, const void* t2b,
    const void* clsw, const void* clsb,
    const int* __restrict__ flag, float* __restrict__ P)
{
    const int f = flag[0];
    const int t = blockIdx.x * 256 + threadIdx.x;
    const int stride = gridDim.x * 256;
#define SEG(src, off, cnt) for (int i = t; i < (cnt); i += stride) P[(off) + i] = ldf(src, i, f)
    SEG(l1w, P_W1, 8192);
    SEG(l2w, P_W2, 4096);
    SEG(l1b, P_B1, 64);
    SEG(l2b, P_B2, 64);
    SEG(a1w, P_A1W, 144);
    SEG(a1b, P_A1B, 1);
    SEG(t1w, P_T1W, 16);
    SEG(t1b, P_T1B, 16);
    SEG(a2w, P_A2W, 144);
    SEG(a2b, P_A2B, 1);
    SEG(t2w, P_T2W, 16);
    SEG(t2b, P_T2B, 16);
    SEG(clsw, P_CLSW, 128);
    SEG(clsb, P_CLSB, 2);
#undef SEG
}

// ---------------------------------------------------------------------------
// Node transform: h = x @ W + b, s_i = h.attw[0:64], s_j = h.attw[64:128]
// One wave per block; thread owns one node (64 f32 accs). W rows wave-uniform.
// DYNAMIC=true: x dtype decided by flag (layer 1). DYNAMIC=false: x is f32.
// ---------------------------------------------------------------------------
template<int INDIM, bool DYNAMIC>
__global__ __launch_bounds__(64) void node_transform(
    const void* __restrict__ xin, const float* __restrict__ P,
    int WOFF, int BOFF, int AOFF, const int* __restrict__ flag,
    float* __restrict__ hout, float* __restrict__ si, float* __restrict__ sj,
    int nnodes)
{
    __shared__ float smem[64 * 129];  // 33 KB; staging (f32 stride 129 / bf16 u32 stride 65), then transpose (stride 68)
    const int lane = threadIdx.x;
    const int base = blockIdx.x * 64;
    const bool xf32 = DYNAMIC ? (flag[0] != 0) : true;

    if (DYNAMIC && !xf32) {
        // bf16 rows: INDIM/8 uint4 per row
        u32* lu = (u32*)smem;
        const uint4* xv = (const uint4*)xin;
        #pragma unroll
        for (int i = 0; i < INDIM / 8; ++i) {
            int v = lane + i * 64;
            int r = v / (INDIM / 8), c = v % (INDIM / 8);
            uint4 val = make_uint4(0u, 0u, 0u, 0u);
            if (base + r < nnodes) val = xv[(size_t)(base + r) * (INDIM / 8) + c];
            int o = r * 65 + c * 4;
            lu[o] = val.x; lu[o + 1] = val.y; lu[o + 2] = val.z; lu[o + 3] = val.w;
        }
    } else {
        // f32 rows: INDIM/4 float4 per row
        const float4* xv = (const float4*)xin;
        #pragma unroll
        for (int i = 0; i < INDIM / 4; ++i) {
            int v = lane + i * 64;
            int r = v / (INDIM / 4), c = v % (INDIM / 4);
            float4 val = make_float4(0.f, 0.f, 0.f, 0.f);
            if (base + r < nnodes) val = xv[(size_t)(base + r) * (INDIM / 4) + c];
            int o = r * 129 + c * 4;
            smem[o] = val.x; smem[o + 1] = val.y; smem[o + 2] = val.z; smem[o + 3] = val.w;
        }
    }
    __syncthreads();

    float acc[64];
    #pragma unroll
    for (int k = 0; k < 64; ++k) acc[k] = P[BOFF + k];

    if (DYNAMIC && !xf32) {
        const u32* row = ((const u32*)smem) + lane * 65;
        for (int m2 = 0; m2 < INDIM / 2; ++m2) {
            u32 xx = row[m2];
            float x0 = bf2f((u16)(xx & 0xffffu));
            float x1 = bf2f((u16)(xx >> 16));
            const float* w = &P[WOFF + (m2 * 2) * 64];
            #pragma unroll
            for (int k = 0; k < 64; ++k) acc[k] = fmaf(x0, w[k], acc[k]);
            #pragma unroll
            for (int k = 0; k < 64; ++k) acc[k] = fmaf(x1, w[64 + k], acc[k]);
        }
    } else {
        const float* row = smem + lane * 129;
        for (int m = 0; m < INDIM; ++m) {
            float xm = row[m];
            const float* w = &P[WOFF + m * 64];
            #pragma unroll
            for (int k = 0; k < 64; ++k) acc[k] = fmaf(xm, w[k], acc[k]);
        }
    }

    float vi = 0.f, vj = 0.f;
    #pragma unroll
    for (int k = 0; k < 64; ++k) vi = fmaf(acc[k], P[AOFF + k], vi);
    #pragma unroll
    for (int k = 0; k < 64; ++k) vj = fmaf(acc[k], P[AOFF + 64 + k], vj);
    int n = base + lane;
    if (n < nnodes) { si[n] = vi; sj[n] = vj; }

    __syncthreads();
    #pragma unroll
    for (int k = 0; k < 64; ++k) smem[lane * 68 + k] = acc[k];
    __syncthreads();
    int r0 = lane >> 4, c4 = lane & 15;
    #pragma unroll
    for (int it = 0; it < 16; ++it) {
        int r = it * 4 + r0;
        int n2 = base + r;
        if (n2 < nnodes) {
            float4 v = *(const float4*)&smem[r * 68 + c4 * 4];
            *(float4*)&hout[(size_t)n2 * 64 + c4 * 4] = v;
        }
    }
}

// ---------------------------------------------------------------------------
// Edge pass 1: alpha1 (leaky), temporal dot for layer 2, degree histogram
// ---------------------------------------------------------------------------
__global__ __launch_bounds__(256) void edge_pass1(
    const int* __restrict__ ei, const void* __restrict__ et,
    const float* __restrict__ si1, const float* __restrict__ sj1,
    const float* __restrict__ P, const int* __restrict__ flag,
    float* __restrict__ alpha1, float* __restrict__ td2out,
    int* __restrict__ deg, int E)
{
    int e = blockIdx.x * 256 + threadIdx.x;
    if (e >= E) return;
    int s = ei[e], d = ei[E + e];
    float t = ldf(et, e, flag[0]);
    float td1 = 0.f, td2 = 0.f;
    #pragma unroll
    for (int k = 0; k < 16; ++k) {
        td1 += __sinf(fmaf(t, P[P_T1W + k], P[P_T1B + k])) * P[P_A1W + 128 + k];
        td2 += __sinf(fmaf(t, P[P_T2W + k], P[P_T2B + k])) * P[P_A2W + 128 + k];
    }
    float a = si1[d] + sj1[s] + td1 + P[P_A1B];
    alpha1[e] = (a > 0.f) ? a : 0.01f * a;
    td2out[e] = td2;
    atomicAdd(&deg[d], 1);
}

// ---------------------------------------------------------------------------
// Edge pass 2: alpha2 from precomputed tdot2 + layer-2 node scalars
// ---------------------------------------------------------------------------
__global__ __launch_bounds__(256) void edge_pass2(
    const int* __restrict__ ei,
    const float* __restrict__ si2, const float* __restrict__ sj2,
    const float* __restrict__ td2, const float* __restrict__ P,
    float* __restrict__ alpha2, int E)
{
    int e = blockIdx.x * 256 + threadIdx.x;
    if (e >= E) return;
    int s = ei[e], d = ei[E + e];
    float a = si2[d] + sj2[s] + td2[e] + P[P_A2B];
    alpha2[e] = (a > 0.f) ? a : 0.01f * a;
}

// ---------------------------------------------------------------------------
// Exclusive scan of deg[0..n) -> offs[0..n]
// ---------------------------------------------------------------------------
__global__ __launch_bounds__(256) void scan_block_sums(
    const int* __restrict__ deg, int* __restrict__ bsum, int n)
{
    __shared__ int s[256];
    int t = threadIdx.x;
    int i = blockIdx.x * 256 + t;
    s[t] = (i < n) ? deg[i] : 0;
    __syncthreads();
    for (int off = 128; off > 0; off >>= 1) {
        if (t < off) s[t] += s[t + off];
        __syncthreads();
    }
    if (t == 0) bsum[blockIdx.x] = s[0];
}

__global__ __launch_bounds__(512) void scan_bsum(int* __restrict__ bsum, int nb)
{
    __shared__ int s[512];
    int t = threadIdx.x;
    int v = (t < nb) ? bsum[t] : 0;
    s[t] = v;
    __syncthreads();
    for (int off = 1; off < 512; off <<= 1) {
        int x = (t >= off) ? s[t - off] : 0;
        __syncthreads();
        s[t] += x;
        __syncthreads();
    }
    bsum[t] = s[t] - v;  // exclusive
}

__global__ __launch_bounds__(256) void scan_final(
    const int* __restrict__ deg, const int* __restrict__ bsum,
    int* __restrict__ offs, int n)
{
    __shared__ int s[256];
    int t = threadIdx.x;
    int i = blockIdx.x * 256 + t;
    int v = (i < n) ? deg[i] : 0;
    s[t] = v;
    __syncthreads();
    for (int off = 1; off < 256; off <<= 1) {
        int x = (t >= off) ? s[t - off] : 0;
        __syncthreads();
        s[t] += x;
        __syncthreads();
    }
    int inc = s[t];
    if (i < n) offs[i] = bsum[blockIdx.x] + inc - v;
    if (i == n - 1) offs[n] = bsum[blockIdx.x] + inc;
}

// ---------------------------------------------------------------------------
// Scatter edge ids into CSR slots
// ---------------------------------------------------------------------------
__global__ __launch_bounds__(256) void scatter_edges(
    const int* __restrict__ ei, const int* __restrict__ offs,
    int* __restrict__ cursor, int* __restrict__ csr, int E)
{
    int e = blockIdx.x * 256 + threadIdx.x;
    if (e >= E) return;
    int d = ei[E + e];
    int p = atomicAdd(&cursor[d], 1);
    csr[offs[d] + p] = e;
}

// ---------------------------------------------------------------------------
// Aggregate: wave per node, lane = feature dim. Online softmax-weighted sum.
// MODE 0 -> relu store to hout; MODE 1 -> classifier to d_out (dtype by flag)
// ---------------------------------------------------------------------------
template<int MODE>
__global__ __launch_bounds__(256) void aggregate(
    const int* __restrict__ offs, const int* __restrict__ csr,
    const int* __restrict__ esrc, const float* __restrict__ alpha,
    const float* __restrict__ hsrc, float* __restrict__ hout,
    void* __restrict__ outp, const float* __restrict__ P,
    const int* __restrict__ flag, int n)
{
    int wave = threadIdx.x >> 6, lane = threadIdx.x & 63;
    int node = blockIdx.x * 4 + wave;
    if (node >= n) return;
    int beg = offs[node], end = offs[node + 1];

    float m = -3.4e38f;
    for (int p = beg + lane; p < end; p += 64) m = fmaxf(m, alpha[csr[p]]);
    #pragma unroll
    for (int o = 32; o > 0; o >>= 1) m = fmaxf(m, __shfl_xor(m, o));

    float ssum = 0.f, acc = 0.f;
    for (int c = beg; c < end; c += 64) {
        int cnt = min(64, end - c);
        float ex = 0.f;
        int src = 0;
        if (lane < cnt) {
            int e = csr[c + lane];
            ex = __expf(alpha[e] - m);
            src = esrc[e];
        }
        ssum += ex;
        for (int j = 0; j < cnt; ++j) {
            float exj = __shfl(ex, j);
            int sj = __shfl(src, j);
            acc = fmaf(exj, hsrc[(size_t)sj * 64 + lane], acc);
        }
    }
    #pragma unroll
    for (int o = 32; o > 0; o >>= 1) ssum += __shfl_xor(ssum, o);

    float r = acc / (ssum + 1e-16f);
    if (MODE == 0) {
        hout[(size_t)node * 64 + lane] = fmaxf(r, 0.f);
    } else {
        float l0 = r * P[P_CLSW + lane * 2];
        float l1 = r * P[P_CLSW + lane * 2 + 1];
        #pragma unroll
        for (int o = 32; o > 0; o >>= 1) {
            l0 += __shfl_xor(l0, o);
            l1 += __shfl_xor(l1, o);
        }
        if (lane == 0) {
            l0 += P[P_CLSB];
            l1 += P[P_CLSB + 1];
            if (flag[0]) {
                ((float2*)outp)[node] = make_float2(l0, l1);
            } else {
                ((u32*)outp)[node] = (u32)f2bf(l0) | ((u32)f2bf(l1) << 16);
            }
        }
    }
}

// ---------------------------------------------------------------------------
extern "C" void kernel_launch(void* const* d_in, const int* in_sizes, int n_in,
                              void* d_out, int out_size, void* d_ws, size_t ws_size,
                              hipStream_t stream)
{
    const void* x    = d_in[0];
    const int*  ei   = (const int*)d_in[1];
    const void* et   = d_in[2];
    const void* l1w  = d_in[3];
    const void* l1b  = d_in[4];
    const void* a1w  = d_in[5];
    const void* a1b  = d_in[6];
    const void* t1w  = d_in[7];
    const void* t1b  = d_in[8];
    const void* l2w  = d_in[9];
    const void* l2b  = d_in[10];
    const void* a2w  = d_in[11];
    const void* a2b  = d_in[12];
    const void* t2w  = d_in[13];
    const void* t2b  = d_in[14];
    const void* clsw = d_in[15];
    const void* clsb = d_in[16];

    const int N = in_sizes[0] / 128;
    const int E = in_sizes[2];

    char* ws = (char*)d_ws;
    size_t off = 0;
    auto A = [&](size_t bytes) -> char* {
        char* p = ws + off;
        off = (off + bytes + 255) & ~(size_t)255;
        return p;
    };
    int*   flag  = (int*)A(256);
    float* P     = (float*)A(P_TOT * 4);
    float* h1    = (float*)A((size_t)N * 64 * 4);  // reused as h2
    float* hag   = (float*)A((size_t)N * 64 * 4);
    float* si1   = (float*)A((size_t)N * 4);
    float* sj1   = (float*)A((size_t)N * 4);
    float* si2   = (float*)A((size_t)N * 4);
    float* sj2   = (float*)A((size_t)N * 4);
    float* alpha = (float*)A((size_t)E * 4);       // alpha1 then alpha2
    float* td2   = (float*)A((size_t)E * 4);
    int*   deg   = (int*)A((size_t)2 * N * 4);     // deg[N] then cursor[N]
    int*   cursor = deg + N;
    int*   offs  = (int*)A((size_t)(N + 1) * 4);
    int*   bsum  = (int*)A(512 * 4);
    int*   csr   = (int*)A((size_t)E * 4);
    (void)ws_size; (void)n_in; (void)out_size;

    hipMemsetAsync(deg, 0, (size_t)2 * N * 4, stream);

    detect_dtype<<<1, 256, 0, stream>>>((const u32*)x, 4096, flag);

    prep_params<<<32, 256, 0, stream>>>(l1w, l1b, a1w, a1b, t1w, t1b,
                                        l2w, l2b, a2w, a2b, t2w, t2b,
                                        clsw, clsb, flag, P);

    node_transform<128, true><<<(N + 63) / 64, 64, 0, stream>>>(
        x, P, P_W1, P_B1, P_A1W, flag, h1, si1, sj1, N);

    edge_pass1<<<(E + 255) / 256, 256, 0, stream>>>(
        ei, et, si1, sj1, P, flag, alpha, td2, deg, E);

    int NB = (N + 255) / 256;
    scan_block_sums<<<NB, 256, 0, stream>>>(deg, bsum, N);
    scan_bsum<<<1, 512, 0, stream>>>(bsum, NB);
    scan_final<<<NB, 256, 0, stream>>>(deg, bsum, offs, N);

    scatter_edges<<<(E + 255) / 256, 256, 0, stream>>>(ei, offs, cursor, csr, E);

    aggregate<0><<<(N + 3) / 4, 256, 0, stream>>>(
        offs, csr, ei, alpha, h1, hag, nullptr, P, flag, N);

    node_transform<64, false><<<(N + 63) / 64, 64, 0, stream>>>(
        hag, P, P_W2, P_B2, P_A2W, flag, h1, si2, sj2, N);

    edge_pass2<<<(E + 255) / 256, 256, 0, stream>>>(
        ei, si2, sj2, td2, P, alpha, E);

    aggregate<1><<<(N + 3) / 4, 256, 0, stream>>>(
        offs, csr, ei, alpha, h1, nullptr, d_out, P, flag, N);
}

// Round 4
// 644.669 us; speedup vs baseline: 1.3609x; 1.3609x over previous
//
#include <hip/hip_runtime.h>

typedef unsigned short u16;
typedef unsigned int u32;

__device__ __forceinline__ float bf2f(u16 u) {
    return __uint_as_float(((u32)u) << 16);
}
__device__ __forceinline__ u16 f2bf(float f) {
    u32 u = __float_as_uint(f);
    u32 r = (u + 0x7fffu + ((u >> 16) & 1u)) >> 16;
    return (u16)r;
}
__device__ __forceinline__ float ldf(const void* p, int i, int isf32) {
    return isf32 ? ((const float*)p)[i] : bf2f(((const u16*)p)[i]);
}

// ---- canonical f32 param block offsets (in floats) ----
#define P_W1   0        // 128x64
#define P_W2   8192     // 64x64
#define P_B1   12288    // 64
#define P_B2   12352    // 64
#define P_A1W  12416    // 144
#define P_A1B  12560    // 1
#define P_T1W  12561    // 16
#define P_T1B  12577    // 16
#define P_A2W  12593    // 144
#define P_A2B  12737    // 1
#define P_T2W  12738    // 16
#define P_T2B  12754    // 16
#define P_CLSW 12770    // 128 (64x2)
#define P_CLSB 12898    // 2
#define P_TOT  12900

// ---------------------------------------------------------------------------
// Detect f32 vs bf16 storage of float tensors (see round-1 notes).
// ---------------------------------------------------------------------------
__global__ __launch_bounds__(256) void detect_dtype(
    const u32* __restrict__ xw, int nwords, int* __restrict__ flag)
{
    __shared__ int sbad;
    if (threadIdx.x == 0) sbad = 0;
    __syncthreads();
    int bad = 0;
    for (int i = threadIdx.x; i < nwords; i += 256) {
        u32 w = xw[i];
        int ea = (w >> 7) & 0xff;
        if (ea >= 0xF0) bad = 1;
    }
    if (bad) sbad = 1;
    __syncthreads();
    if (threadIdx.x == 0) flag[0] = sbad;
}

// ---------------------------------------------------------------------------
// Convert all small parameter tensors into one f32 param block.
// ---------------------------------------------------------------------------
__global__ __launch_bounds__(256) void prep_params(
    const void* l1w, const void* l1b, const void* a1w, const void* a1b,
    const void* t1w, const void* t1b, const void* l2w, const void* l2b,
    const void* a2w, const void* a2b, const void* t2w, const void* t2b,
    const void* clsw, const void* clsb,
    const int* __restrict__ flag, float* __restrict__ P)
{
    const int f = flag[0];
    const int t = blockIdx.x * 256 + threadIdx.x;
    const int stride = gridDim.x * 256;
#define SEG(src, off, cnt) for (int i = t; i < (cnt); i += stride) P[(off) + i] = ldf(src, i, f)
    SEG(l1w, P_W1, 8192);
    SEG(l2w, P_W2, 4096);
    SEG(l1b, P_B1, 64);
    SEG(l2b, P_B2, 64);
    SEG(a1w, P_A1W, 144);
    SEG(a1b, P_A1B, 1);
    SEG(t1w, P_T1W, 16);
    SEG(t1b, P_T1B, 16);
    SEG(a2w, P_A2W, 144);
    SEG(a2b, P_A2B, 1);
    SEG(t2w, P_T2W, 16);
    SEG(t2b, P_T2B, 16);
    SEG(clsw, P_CLSW, 128);
    SEG(clsb, P_CLSB, 2);
#undef SEG
}

// ---------------------------------------------------------------------------
// Node transform as tiled GEMM: h[N,64] = x[N,K] @ W[K,64] + b, fused
// si = h.aw[0:64], sj = h.aw[64:128].
// Block: 256 threads, tile BM=64 nodes x BN=64 outs, 4x4 regs/thread, BK=32.
// W staged fully in LDS (broadcast reads); A-tile staged transposed.
// ---------------------------------------------------------------------------
template<int K, bool DYNAMIC>
__global__ __launch_bounds__(256) void node_gemm(
    const void* __restrict__ xin, const float* __restrict__ P,
    int WOFF, int BOFF, int AOFF, const int* __restrict__ flag,
    float* __restrict__ hout, float* __restrict__ si, float* __restrict__ sj,
    int nnodes)
{
    __shared__ float Ws[K * 64];
    __shared__ float As[32][66];   // [k][node], stride 66 -> 2-way banks (free)
    const int t = threadIdx.x;
    const int tx = t & 15;         // output group: cols tx*4..tx*4+3
    const int ty = t >> 4;         // node group:  rows ty*4..ty*4+3
    const int base = blockIdx.x * 64;
    const bool xf32 = DYNAMIC ? (flag[0] != 0) : true;

    // stage W (coalesced float4)
    for (int i = t * 4; i < K * 64; i += 1024)
        *(float4*)&Ws[i] = *(const float4*)&P[WOFF + i];

    float acc[4][4];
    #pragma unroll
    for (int r = 0; r < 4; ++r)
        #pragma unroll
        for (int c = 0; c < 4; ++c) acc[r][c] = 0.f;

    for (int k0 = 0; k0 < K; k0 += 32) {
        __syncthreads();
        if (!DYNAMIC || xf32) {
            // f32 x: 64 rows x 32 cols = 512 float4; 2 per thread
            #pragma unroll
            for (int it = 0; it < 2; ++it) {
                int idx = t + it * 256;
                int row = idx >> 3, cq = (idx & 7) * 4;
                float4 v = make_float4(0.f, 0.f, 0.f, 0.f);
                if (base + row < nnodes)
                    v = *(const float4*)&((const float*)xin)[(size_t)(base + row) * K + k0 + cq];
                As[cq + 0][row] = v.x; As[cq + 1][row] = v.y;
                As[cq + 2][row] = v.z; As[cq + 3][row] = v.w;
            }
        } else {
            // bf16 x: 64 rows x 32 halves = 256 uint4; 1 per thread
            int row = t >> 2, q = (t & 3) * 8;
            uint4 v = make_uint4(0u, 0u, 0u, 0u);
            if (base + row < nnodes)
                v = *(const uint4*)&((const u16*)xin)[(size_t)(base + row) * K + k0 + q];
            As[q + 0][row] = bf2f((u16)(v.x & 0xffffu));
            As[q + 1][row] = bf2f((u16)(v.x >> 16));
            As[q + 2][row] = bf2f((u16)(v.y & 0xffffu));
            As[q + 3][row] = bf2f((u16)(v.y >> 16));
            As[q + 4][row] = bf2f((u16)(v.z & 0xffffu));
            As[q + 5][row] = bf2f((u16)(v.z >> 16));
            As[q + 6][row] = bf2f((u16)(v.w & 0xffffu));
            As[q + 7][row] = bf2f((u16)(v.w >> 16));
        }
        __syncthreads();

        #pragma unroll
        for (int k = 0; k < 32; ++k) {
            float2 a01 = *(float2*)&As[k][ty * 4];
            float2 a23 = *(float2*)&As[k][ty * 4 + 2];
            // FIX (round 3): W row is the GLOBAL k index (k0 + k), not tile-local k.
            float4 b = *(float4*)&Ws[(k0 + k) * 64 + tx * 4];
            float a[4] = { a01.x, a01.y, a23.x, a23.y };
            float bb[4] = { b.x, b.y, b.z, b.w };
            #pragma unroll
            for (int r = 0; r < 4; ++r)
                #pragma unroll
                for (int c = 0; c < 4; ++c)
                    acc[r][c] = fmaf(a[r], bb[c], acc[r][c]);
        }
    }

    // add bias
    #pragma unroll
    for (int c = 0; c < 4; ++c) {
        float bc = P[BOFF + tx * 4 + c];
        #pragma unroll
        for (int r = 0; r < 4; ++r) acc[r][c] += bc;
    }

    // fused attention scalars: reduce over the 16 tx lanes (same wave)
    float vi[4], vj[4];
    #pragma unroll
    for (int r = 0; r < 4; ++r) {
        float a_i = 0.f, a_j = 0.f;
        #pragma unroll
        for (int c = 0; c < 4; ++c) {
            a_i = fmaf(acc[r][c], P[AOFF + tx * 4 + c], a_i);
            a_j = fmaf(acc[r][c], P[AOFF + 64 + tx * 4 + c], a_j);
        }
        vi[r] = a_i; vj[r] = a_j;
    }
    #pragma unroll
    for (int o = 1; o < 16; o <<= 1) {
        #pragma unroll
        for (int r = 0; r < 4; ++r) {
            vi[r] += __shfl_xor(vi[r], o);
            vj[r] += __shfl_xor(vj[r], o);
        }
    }

    #pragma unroll
    for (int r = 0; r < 4; ++r) {
        int node = base + ty * 4 + r;
        if (node < nnodes) {
            *(float4*)&hout[(size_t)node * 64 + tx * 4] =
                make_float4(acc[r][0], acc[r][1], acc[r][2], acc[r][3]);
            if (tx == 0) { si[node] = vi[r]; sj[node] = vj[r]; }
        }
    }
}

// ---------------------------------------------------------------------------
// Edge pass 1: alpha1 (leaky), temporal dot for layer 2, degree histogram
// ---------------------------------------------------------------------------
__global__ __launch_bounds__(256) void edge_pass1(
    const int* __restrict__ ei, const void* __restrict__ et,
    const float* __restrict__ si1, const float* __restrict__ sj1,
    const float* __restrict__ P, const int* __restrict__ flag,
    float* __restrict__ alpha1, float* __restrict__ td2out,
    int* __restrict__ deg, int E)
{
    int e = blockIdx.x * 256 + threadIdx.x;
    if (e >= E) return;
    int s = ei[e], d = ei[E + e];
    float t = ldf(et, e, flag[0]);
    float td1 = 0.f, td2 = 0.f;
    #pragma unroll
    for (int k = 0; k < 16; ++k) {
        td1 += __sinf(fmaf(t, P[P_T1W + k], P[P_T1B + k])) * P[P_A1W + 128 + k];
        td2 += __sinf(fmaf(t, P[P_T2W + k], P[P_T2B + k])) * P[P_A2W + 128 + k];
    }
    float a = si1[d] + sj1[s] + td1 + P[P_A1B];
    alpha1[e] = (a > 0.f) ? a : 0.01f * a;
    td2out[e] = td2;
    atomicAdd(&deg[d], 1);
}

// ---------------------------------------------------------------------------
// Edge pass 2: alpha2 from precomputed tdot2 + layer-2 node scalars
// ---------------------------------------------------------------------------
__global__ __launch_bounds__(256) void edge_pass2(
    const int* __restrict__ ei,
    const float* __restrict__ si2, const float* __restrict__ sj2,
    const float* __restrict__ td2, const float* __restrict__ P,
    float* __restrict__ alpha2, int E)
{
    int e = blockIdx.x * 256 + threadIdx.x;
    if (e >= E) return;
    int s = ei[e], d = ei[E + e];
    float a = si2[d] + sj2[s] + td2[e] + P[P_A2B];
    alpha2[e] = (a > 0.f) ? a : 0.01f * a;
}

// ---------------------------------------------------------------------------
// Exclusive scan of deg[0..n) -> offs[0..n]
// ---------------------------------------------------------------------------
__global__ __launch_bounds__(256) void scan_block_sums(
    const int* __restrict__ deg, int* __restrict__ bsum, int n)
{
    __shared__ int s[256];
    int t = threadIdx.x;
    int i = blockIdx.x * 256 + t;
    s[t] = (i < n) ? deg[i] : 0;
    __syncthreads();
    for (int off = 128; off > 0; off >>= 1) {
        if (t < off) s[t] += s[t + off];
        __syncthreads();
    }
    if (t == 0) bsum[blockIdx.x] = s[0];
}

__global__ __launch_bounds__(512) void scan_bsum(int* __restrict__ bsum, int nb)
{
    __shared__ int s[512];
    int t = threadIdx.x;
    int v = (t < nb) ? bsum[t] : 0;
    s[t] = v;
    __syncthreads();
    for (int off = 1; off < 512; off <<= 1) {
        int x = (t >= off) ? s[t - off] : 0;
        __syncthreads();
        s[t] += x;
        __syncthreads();
    }
    bsum[t] = s[t] - v;  // exclusive
}

__global__ __launch_bounds__(256) void scan_final(
    const int* __restrict__ deg, const int* __restrict__ bsum,
    int* __restrict__ offs, int n)
{
    __shared__ int s[256];
    int t = threadIdx.x;
    int i = blockIdx.x * 256 + t;
    int v = (i < n) ? deg[i] : 0;
    s[t] = v;
    __syncthreads();
    for (int off = 1; off < 256; off <<= 1) {
        int x = (t >= off) ? s[t - off] : 0;
        __syncthreads();
        s[t] += x;
        __syncthreads();
    }
    int inc = s[t];
    if (i < n) offs[i] = bsum[blockIdx.x] + inc - v;
    if (i == n - 1) offs[n] = bsum[blockIdx.x] + inc;
}

// ---------------------------------------------------------------------------
// Scatter edge ids into CSR slots
// ---------------------------------------------------------------------------
__global__ __launch_bounds__(256) void scatter_edges(
    const int* __restrict__ ei, const int* __restrict__ offs,
    int* __restrict__ cursor, int* __restrict__ csr, int E)
{
    int e = blockIdx.x * 256 + threadIdx.x;
    if (e >= E) return;
    int d = ei[E + e];
    int p = atomicAdd(&cursor[d], 1);
    csr[offs[d] + p] = e;
}

// ---------------------------------------------------------------------------
// Aggregate: wave per node, lane = feature dim. Softmax-weighted sum.
// MODE 0 -> relu store to hout; MODE 1 -> classifier to d_out (dtype by flag)
// ---------------------------------------------------------------------------
template<int MODE>
__global__ __launch_bounds__(256) void aggregate(
    const int* __restrict__ offs, const int* __restrict__ csr,
    const int* __restrict__ esrc, const float* __restrict__ alpha,
    const float* __restrict__ hsrc, float* __restrict__ hout,
    void* __restrict__ outp, const float* __restrict__ P,
    const int* __restrict__ flag, int n)
{
    int wave = threadIdx.x >> 6, lane = threadIdx.x & 63;
    int node = blockIdx.x * 4 + wave;
    if (node >= n) return;
    int beg = offs[node], end = offs[node + 1];

    float m = -3.4e38f;
    for (int p = beg + lane; p < end; p += 64) m = fmaxf(m, alpha[csr[p]]);
    #pragma unroll
    for (int o = 32; o > 0; o >>= 1) m = fmaxf(m, __shfl_xor(m, o));

    float ssum = 0.f, acc = 0.f;
    for (int c = beg; c < end; c += 64) {
        int cnt = min(64, end - c);
        float ex = 0.f;
        int src = 0;
        if (lane < cnt) {
            int e = csr[c + lane];
            ex = __expf(alpha[e] - m);
            src = esrc[e];
        }
        ssum += ex;
        for (int j = 0; j < cnt; ++j) {
            float exj = __shfl(ex, j);
            int sj = __shfl(src, j);
            acc = fmaf(exj, hsrc[(size_t)sj * 64 + lane], acc);
        }
    }
    #pragma unroll
    for (int o = 32; o > 0; o >>= 1) ssum += __shfl_xor(ssum, o);

    float r = acc / (ssum + 1e-16f);
    if (MODE == 0) {
        hout[(size_t)node * 64 + lane] = fmaxf(r, 0.f);
    } else {
        float l0 = r * P[P_CLSW + lane * 2];
        float l1 = r * P[P_CLSW + lane * 2 + 1];
        #pragma unroll
        for (int o = 32; o > 0; o >>= 1) {
            l0 += __shfl_xor(l0, o);
            l1 += __shfl_xor(l1, o);
        }
        if (lane == 0) {
            l0 += P[P_CLSB];
            l1 += P[P_CLSB + 1];
            if (flag[0]) {
                ((float2*)outp)[node] = make_float2(l0, l1);
            } else {
                ((u32*)outp)[node] = (u32)f2bf(l0) | ((u32)f2bf(l1) << 16);
            }
        }
    }
}

// ---------------------------------------------------------------------------
extern "C" void kernel_launch(void* const* d_in, const int* in_sizes, int n_in,
                              void* d_out, int out_size, void* d_ws, size_t ws_size,
                              hipStream_t stream)
{
    const void* x    = d_in[0];
    const int*  ei   = (const int*)d_in[1];
    const void* et   = d_in[2];
    const void* l1w  = d_in[3];
    const void* l1b  = d_in[4];
    const void* a1w  = d_in[5];
    const void* a1b  = d_in[6];
    const void* t1w  = d_in[7];
    const void* t1b  = d_in[8];
    const void* l2w  = d_in[9];
    const void* l2b  = d_in[10];
    const void* a2w  = d_in[11];
    const void* a2b  = d_in[12];
    const void* t2w  = d_in[13];
    const void* t2b  = d_in[14];
    const void* clsw = d_in[15];
    const void* clsb = d_in[16];

    const int N = in_sizes[0] / 128;
    const int E = in_sizes[2];

    char* ws = (char*)d_ws;
    size_t off = 0;
    auto A = [&](size_t bytes) -> char* {
        char* p = ws + off;
        off = (off + bytes + 255) & ~(size_t)255;
        return p;
    };
    int*   flag  = (int*)A(256);
    float* P     = (float*)A(P_TOT * 4);
    float* h1    = (float*)A((size_t)N * 64 * 4);  // reused as h2
    float* hag   = (float*)A((size_t)N * 64 * 4);
    float* si1   = (float*)A((size_t)N * 4);
    float* sj1   = (float*)A((size_t)N * 4);
    float* si2   = (float*)A((size_t)N * 4);
    float* sj2   = (float*)A((size_t)N * 4);
    float* alpha = (float*)A((size_t)E * 4);       // alpha1 then alpha2
    float* td2   = (float*)A((size_t)E * 4);
    int*   deg   = (int*)A((size_t)2 * N * 4);     // deg[N] then cursor[N]
    int*   cursor = deg + N;
    int*   offs  = (int*)A((size_t)(N + 1) * 4);
    int*   bsum  = (int*)A(512 * 4);
    int*   csr   = (int*)A((size_t)E * 4);
    (void)ws_size; (void)n_in; (void)out_size;

    hipMemsetAsync(deg, 0, (size_t)2 * N * 4, stream);

    detect_dtype<<<1, 256, 0, stream>>>((const u32*)x, 4096, flag);

    prep_params<<<32, 256, 0, stream>>>(l1w, l1b, a1w, a1b, t1w, t1b,
                                        l2w, l2b, a2w, a2b, t2w, t2b,
                                        clsw, clsb, flag, P);

    node_gemm<128, true><<<(N + 63) / 64, 256, 0, stream>>>(
        x, P, P_W1, P_B1, P_A1W, flag, h1, si1, sj1, N);

    edge_pass1<<<(E + 255) / 256, 256, 0, stream>>>(
        ei, et, si1, sj1, P, flag, alpha, td2, deg, E);

    int NB = (N + 255) / 256;
    scan_block_sums<<<NB, 256, 0, stream>>>(deg, bsum, N);
    scan_bsum<<<1, 512, 0, stream>>>(bsum, NB);
    scan_final<<<NB, 256, 0, stream>>>(deg, bsum, offs, N);

    scatter_edges<<<(E + 255) / 256, 256, 0, stream>>>(ei, offs, cursor, csr, E);

    aggregate<0><<<(N + 3) / 4, 256, 0, stream>>>(
        offs, csr, ei, alpha, h1, hag, nullptr, P, flag, N);

    node_gemm<64, false><<<(N + 63) / 64, 256, 0, stream>>>(
        hag, P, P_W2, P_B2, P_A2W, flag, h1, si2, sj2, N);

    edge_pass2<<<(E + 255) / 256, 256, 0, stream>>>(
        ei, si2, sj2, td2, P, alpha, E);

    aggregate<1><<<(N + 3) / 4, 256, 0, stream>>>(
        offs, csr, ei, alpha, h1, nullptr, d_out, P, flag, N);
}

// Round 5
// 512.112 us; speedup vs baseline: 1.7131x; 1.2588x over previous
//
#include <hip/hip_runtime.h>

typedef unsigned short u16;
typedef unsigned int u32;

__device__ __forceinline__ float bf2f(u16 u) {
    return __uint_as_float(((u32)u) << 16);
}
__device__ __forceinline__ u16 f2bf(float f) {
    u32 u = __float_as_uint(f);
    u32 r = (u + 0x7fffu + ((u >> 16) & 1u)) >> 16;
    return (u16)r;
}
__device__ __forceinline__ float ldf(const void* p, int i, int isf32) {
    return isf32 ? ((const float*)p)[i] : bf2f(((const u16*)p)[i]);
}

// ---- canonical f32 param block offsets (in floats) ----
#define P_W1   0        // 128x64
#define P_W2   8192     // 64x64
#define P_B1   12288    // 64
#define P_B2   12352    // 64
#define P_A1W  12416    // 144
#define P_A1B  12560    // 1
#define P_T1W  12561    // 16
#define P_T1B  12577    // 16
#define P_A2W  12593    // 144
#define P_A2B  12737    // 1
#define P_T2W  12738    // 16
#define P_T2B  12754    // 16
#define P_CLSW 12770    // 128 (64x2)
#define P_CLSB 12898    // 2
#define P_TOT  12900

// ---------------------------------------------------------------------------
// Detect f32 vs bf16 storage of float tensors (see round-1 notes).
// ---------------------------------------------------------------------------
__global__ __launch_bounds__(256) void detect_dtype(
    const u32* __restrict__ xw, int nwords, int* __restrict__ flag)
{
    __shared__ int sbad;
    if (threadIdx.x == 0) sbad = 0;
    __syncthreads();
    int bad = 0;
    for (int i = threadIdx.x; i < nwords; i += 256) {
        u32 w = xw[i];
        int ea = (w >> 7) & 0xff;
        if (ea >= 0xF0) bad = 1;
    }
    if (bad) sbad = 1;
    __syncthreads();
    if (threadIdx.x == 0) flag[0] = sbad;
}

// ---------------------------------------------------------------------------
// Convert all small parameter tensors into one f32 param block.
// ---------------------------------------------------------------------------
__global__ __launch_bounds__(256) void prep_params(
    const void* l1w, const void* l1b, const void* a1w, const void* a1b,
    const void* t1w, const void* t1b, const void* l2w, const void* l2b,
    const void* a2w, const void* a2b, const void* t2w, const void* t2b,
    const void* clsw, const void* clsb,
    const int* __restrict__ flag, float* __restrict__ P)
{
    const int f = flag[0];
    const int t = blockIdx.x * 256 + threadIdx.x;
    const int stride = gridDim.x * 256;
#define SEG(src, off, cnt) for (int i = t; i < (cnt); i += stride) P[(off) + i] = ldf(src, i, f)
    SEG(l1w, P_W1, 8192);
    SEG(l2w, P_W2, 4096);
    SEG(l1b, P_B1, 64);
    SEG(l2b, P_B2, 64);
    SEG(a1w, P_A1W, 144);
    SEG(a1b, P_A1B, 1);
    SEG(t1w, P_T1W, 16);
    SEG(t1b, P_T1B, 16);
    SEG(a2w, P_A2W, 144);
    SEG(a2b, P_A2B, 1);
    SEG(t2w, P_T2W, 16);
    SEG(t2b, P_T2B, 16);
    SEG(clsw, P_CLSW, 128);
    SEG(clsb, P_CLSB, 2);
#undef SEG
}

// ---------------------------------------------------------------------------
// Node transform as tiled GEMM: h[N,64] = x[N,K] @ W[K,64] + b, fused
// si = h.aw[0:64], sj = h.aw[64:128].
// Output h is written as PACKED BF16 rows (32 u32 per node) for the
// aggregate's gather (halves gather bytes). si/sj from full-f32 acc.
// ---------------------------------------------------------------------------
template<int K, bool DYNAMIC>
__global__ __launch_bounds__(256) void node_gemm(
    const void* __restrict__ xin, const float* __restrict__ P,
    int WOFF, int BOFF, int AOFF, const int* __restrict__ flag,
    u32* __restrict__ houtb, float* __restrict__ si, float* __restrict__ sj,
    int nnodes)
{
    __shared__ float Ws[K * 64];
    __shared__ float As[32][66];   // [k][node], stride 66 -> 2-way banks (free)
    const int t = threadIdx.x;
    const int tx = t & 15;         // output group: cols tx*4..tx*4+3
    const int ty = t >> 4;         // node group:  rows ty*4..ty*4+3
    const int base = blockIdx.x * 64;
    const bool xf32 = DYNAMIC ? (flag[0] != 0) : true;

    // stage W (coalesced float4)
    for (int i = t * 4; i < K * 64; i += 1024)
        *(float4*)&Ws[i] = *(const float4*)&P[WOFF + i];

    float acc[4][4];
    #pragma unroll
    for (int r = 0; r < 4; ++r)
        #pragma unroll
        for (int c = 0; c < 4; ++c) acc[r][c] = 0.f;

    for (int k0 = 0; k0 < K; k0 += 32) {
        __syncthreads();
        if (!DYNAMIC || xf32) {
            #pragma unroll
            for (int it = 0; it < 2; ++it) {
                int idx = t + it * 256;
                int row = idx >> 3, cq = (idx & 7) * 4;
                float4 v = make_float4(0.f, 0.f, 0.f, 0.f);
                if (base + row < nnodes)
                    v = *(const float4*)&((const float*)xin)[(size_t)(base + row) * K + k0 + cq];
                As[cq + 0][row] = v.x; As[cq + 1][row] = v.y;
                As[cq + 2][row] = v.z; As[cq + 3][row] = v.w;
            }
        } else {
            int row = t >> 2, q = (t & 3) * 8;
            uint4 v = make_uint4(0u, 0u, 0u, 0u);
            if (base + row < nnodes)
                v = *(const uint4*)&((const u16*)xin)[(size_t)(base + row) * K + k0 + q];
            As[q + 0][row] = bf2f((u16)(v.x & 0xffffu));
            As[q + 1][row] = bf2f((u16)(v.x >> 16));
            As[q + 2][row] = bf2f((u16)(v.y & 0xffffu));
            As[q + 3][row] = bf2f((u16)(v.y >> 16));
            As[q + 4][row] = bf2f((u16)(v.z & 0xffffu));
            As[q + 5][row] = bf2f((u16)(v.z >> 16));
            As[q + 6][row] = bf2f((u16)(v.w & 0xffffu));
            As[q + 7][row] = bf2f((u16)(v.w >> 16));
        }
        __syncthreads();

        #pragma unroll
        for (int k = 0; k < 32; ++k) {
            float2 a01 = *(float2*)&As[k][ty * 4];
            float2 a23 = *(float2*)&As[k][ty * 4 + 2];
            float4 b = *(float4*)&Ws[(k0 + k) * 64 + tx * 4];  // GLOBAL k row
            float a[4] = { a01.x, a01.y, a23.x, a23.y };
            float bb[4] = { b.x, b.y, b.z, b.w };
            #pragma unroll
            for (int r = 0; r < 4; ++r)
                #pragma unroll
                for (int c = 0; c < 4; ++c)
                    acc[r][c] = fmaf(a[r], bb[c], acc[r][c]);
        }
    }

    // add bias
    #pragma unroll
    for (int c = 0; c < 4; ++c) {
        float bc = P[BOFF + tx * 4 + c];
        #pragma unroll
        for (int r = 0; r < 4; ++r) acc[r][c] += bc;
    }

    // fused attention scalars: reduce over the 16 tx lanes (same wave)
    float vi[4], vj[4];
    #pragma unroll
    for (int r = 0; r < 4; ++r) {
        float a_i = 0.f, a_j = 0.f;
        #pragma unroll
        for (int c = 0; c < 4; ++c) {
            a_i = fmaf(acc[r][c], P[AOFF + tx * 4 + c], a_i);
            a_j = fmaf(acc[r][c], P[AOFF + 64 + tx * 4 + c], a_j);
        }
        vi[r] = a_i; vj[r] = a_j;
    }
    #pragma unroll
    for (int o = 1; o < 16; o <<= 1) {
        #pragma unroll
        for (int r = 0; r < 4; ++r) {
            vi[r] += __shfl_xor(vi[r], o);
            vj[r] += __shfl_xor(vj[r], o);
        }
    }

    #pragma unroll
    for (int r = 0; r < 4; ++r) {
        int node = base + ty * 4 + r;
        if (node < nnodes) {
            u32 w0 = (u32)f2bf(acc[r][0]) | ((u32)f2bf(acc[r][1]) << 16);
            u32 w1 = (u32)f2bf(acc[r][2]) | ((u32)f2bf(acc[r][3]) << 16);
            *(uint2*)&houtb[(size_t)node * 32 + tx * 2] = make_uint2(w0, w1);
            if (tx == 0) { si[node] = vi[r]; sj[node] = vj[r]; }
        }
    }
}

// ---------------------------------------------------------------------------
// Edge pass 1: alpha1 (leaky), temporal dot for layer 2, degree histogram
// ---------------------------------------------------------------------------
__global__ __launch_bounds__(256) void edge_pass1(
    const int* __restrict__ ei, const void* __restrict__ et,
    const float* __restrict__ si1, const float* __restrict__ sj1,
    const float* __restrict__ P, const int* __restrict__ flag,
    float* __restrict__ alpha1, float* __restrict__ td2out,
    int* __restrict__ deg, int E)
{
    int e = blockIdx.x * 256 + threadIdx.x;
    if (e >= E) return;
    int s = ei[e], d = ei[E + e];
    float t = ldf(et, e, flag[0]);
    float td1 = 0.f, td2 = 0.f;
    #pragma unroll
    for (int k = 0; k < 16; ++k) {
        td1 += __sinf(fmaf(t, P[P_T1W + k], P[P_T1B + k])) * P[P_A1W + 128 + k];
        td2 += __sinf(fmaf(t, P[P_T2W + k], P[P_T2B + k])) * P[P_A2W + 128 + k];
    }
    float a = si1[d] + sj1[s] + td1 + P[P_A1B];
    alpha1[e] = (a > 0.f) ? a : 0.01f * a;
    td2out[e] = td2;
    atomicAdd(&deg[d], 1);
}

// ---------------------------------------------------------------------------
// Edge pass 2: alpha2 from precomputed tdot2 + layer-2 node scalars
// ---------------------------------------------------------------------------
__global__ __launch_bounds__(256) void edge_pass2(
    const int* __restrict__ ei,
    const float* __restrict__ si2, const float* __restrict__ sj2,
    const float* __restrict__ td2, const float* __restrict__ P,
    float* __restrict__ alpha2, int E)
{
    int e = blockIdx.x * 256 + threadIdx.x;
    if (e >= E) return;
    int s = ei[e], d = ei[E + e];
    float a = si2[d] + sj2[s] + td2[e] + P[P_A2B];
    alpha2[e] = (a > 0.f) ? a : 0.01f * a;
}

// ---------------------------------------------------------------------------
// Exclusive scan of deg[0..n) -> offs[0..n]
// ---------------------------------------------------------------------------
__global__ __launch_bounds__(256) void scan_block_sums(
    const int* __restrict__ deg, int* __restrict__ bsum, int n)
{
    __shared__ int s[256];
    int t = threadIdx.x;
    int i = blockIdx.x * 256 + t;
    s[t] = (i < n) ? deg[i] : 0;
    __syncthreads();
    for (int off = 128; off > 0; off >>= 1) {
        if (t < off) s[t] += s[t + off];
        __syncthreads();
    }
    if (t == 0) bsum[blockIdx.x] = s[0];
}

__global__ __launch_bounds__(512) void scan_bsum(int* __restrict__ bsum, int nb)
{
    __shared__ int s[512];
    int t = threadIdx.x;
    int v = (t < nb) ? bsum[t] : 0;
    s[t] = v;
    __syncthreads();
    for (int off = 1; off < 512; off <<= 1) {
        int x = (t >= off) ? s[t - off] : 0;
        __syncthreads();
        s[t] += x;
        __syncthreads();
    }
    bsum[t] = s[t] - v;  // exclusive
}

__global__ __launch_bounds__(256) void scan_final(
    const int* __restrict__ deg, const int* __restrict__ bsum,
    int* __restrict__ offs, int n)
{
    __shared__ int s[256];
    int t = threadIdx.x;
    int i = blockIdx.x * 256 + t;
    int v = (i < n) ? deg[i] : 0;
    s[t] = v;
    __syncthreads();
    for (int off = 1; off < 256; off <<= 1) {
        int x = (t >= off) ? s[t - off] : 0;
        __syncthreads();
        s[t] += x;
        __syncthreads();
    }
    int inc = s[t];
    if (i < n) offs[i] = bsum[blockIdx.x] + inc - v;
    if (i == n - 1) offs[n] = bsum[blockIdx.x] + inc;
}

// ---------------------------------------------------------------------------
// Scatter (src, edge_id) pairs into CSR slots
// ---------------------------------------------------------------------------
__global__ __launch_bounds__(256) void scatter_edges(
    const int* __restrict__ ei, const int* __restrict__ offs,
    int* __restrict__ cursor, int2* __restrict__ csr2, int E)
{
    int e = blockIdx.x * 256 + threadIdx.x;
    if (e >= E) return;
    int s = ei[e], d = ei[E + e];
    int p = atomicAdd(&cursor[d], 1);
    csr2[offs[d] + p] = make_int2(s, e);
}

// ---------------------------------------------------------------------------
// Aggregate: wave per node. Phase A gathers alpha once per edge into an LDS
// cache (src, alpha). Phase B: half-wave per edge, lane covers 2 bf16
// features, groups of 8 edges with 4 row-loads in flight.
// MODE 0 -> relu store f32 rows; MODE 1 -> classifier to d_out.
// ---------------------------------------------------------------------------
#define CAP 512

template<int MODE>
__global__ __launch_bounds__(256) void aggregate(
    const int* __restrict__ offs, const int2* __restrict__ csr2,
    const float* __restrict__ alpha, const u32* __restrict__ hb,
    float* __restrict__ hout, void* __restrict__ outp,
    const float* __restrict__ P, const int* __restrict__ flag, int n)
{
    __shared__ int2 cache[4][CAP];
    const int wave = threadIdx.x >> 6, lane = threadIdx.x & 63;
    const int node = blockIdx.x * 4 + wave;
    const bool active = node < n;
    int beg = 0, end = 0;
    if (active) { beg = offs[node]; end = offs[node + 1]; }
    const int deg = end - beg;
    int2* cw = cache[wave];

    // phase A: gather alpha once per edge, fill LDS cache, wave-max
    float m = -3.4e38f;
    for (int idx = lane; idx < deg; idx += 64) {
        int2 se = csr2[beg + idx];
        float a = alpha[se.y];
        if (idx < CAP) cw[idx] = make_int2(se.x, __float_as_int(a));
        m = fmaxf(m, a);
    }
    #pragma unroll
    for (int o = 32; o > 0; o >>= 1) m = fmaxf(m, __shfl_xor(m, o));
    __syncthreads();   // cache visible to whole wave (and block)

    // softmax denominator
    float ssum = 0.f;
    for (int idx = lane; idx < deg; idx += 64) {
        float a = (idx < CAP) ? __int_as_float(cw[idx].y)
                              : alpha[csr2[beg + idx].y];
        ssum += __expf(a - m);
    }
    #pragma unroll
    for (int o = 32; o > 0; o >>= 1) ssum += __shfl_xor(ssum, o);

    // phase B: half-wave per edge; lane covers features 2*fl, 2*fl+1
    const int half = lane >> 5;
    const int fl = lane & 31;
    float ax = 0.f, ay = 0.f;
    int j0 = 0;
    if (deg <= CAP) {
        for (; j0 + 8 <= deg; j0 += 8) {
            int2 s0 = cw[j0 + 0 + half];
            int2 s1 = cw[j0 + 2 + half];
            int2 s2 = cw[j0 + 4 + half];
            int2 s3 = cw[j0 + 6 + half];
            u32 p0 = hb[(size_t)s0.x * 32 + fl];
            u32 p1 = hb[(size_t)s1.x * 32 + fl];
            u32 p2 = hb[(size_t)s2.x * 32 + fl];
            u32 p3 = hb[(size_t)s3.x * 32 + fl];
            float e0 = __expf(__int_as_float(s0.y) - m);
            float e1 = __expf(__int_as_float(s1.y) - m);
            float e2 = __expf(__int_as_float(s2.y) - m);
            float e3 = __expf(__int_as_float(s3.y) - m);
            ax = fmaf(e0, bf2f((u16)(p0 & 0xffffu)), ax);
            ay = fmaf(e0, bf2f((u16)(p0 >> 16)), ay);
            ax = fmaf(e1, bf2f((u16)(p1 & 0xffffu)), ax);
            ay = fmaf(e1, bf2f((u16)(p1 >> 16)), ay);
            ax = fmaf(e2, bf2f((u16)(p2 & 0xffffu)), ax);
            ay = fmaf(e2, bf2f((u16)(p2 >> 16)), ay);
            ax = fmaf(e3, bf2f((u16)(p3 & 0xffffu)), ax);
            ay = fmaf(e3, bf2f((u16)(p3 >> 16)), ay);
        }
    }
    for (; j0 < deg; j0 += 2) {
        int j = j0 + half;
        float ex = 0.f;
        int src = 0;
        if (j < deg) {
            int2 sa;
            if (j < CAP) sa = cw[j];
            else { int2 se = csr2[beg + j]; sa = make_int2(se.x, __float_as_int(alpha[se.y])); }
            src = sa.x;
            ex = __expf(__int_as_float(sa.y) - m);
        }
        u32 pk = hb[(size_t)src * 32 + fl];
        ax = fmaf(ex, bf2f((u16)(pk & 0xffffu)), ax);
        ay = fmaf(ex, bf2f((u16)(pk >> 16)), ay);
    }
    ax += __shfl_xor(ax, 32);
    ay += __shfl_xor(ay, 32);

    if (!active) return;
    float inv = 1.0f / (ssum + 1e-16f);

    if (MODE == 0) {
        if (lane < 32) {
            float2 v = make_float2(fmaxf(ax * inv, 0.f), fmaxf(ay * inv, 0.f));
            *(float2*)&hout[(size_t)node * 64 + fl * 2] = v;
        }
    } else {
        float r0 = ax * inv, r1 = ay * inv;
        // clsw layout [64][2]: feature f -> P_CLSW + 2f + out
        float l0 = r0 * P[P_CLSW + 4 * fl]     + r1 * P[P_CLSW + 4 * fl + 2];
        float l1 = r0 * P[P_CLSW + 4 * fl + 1] + r1 * P[P_CLSW + 4 * fl + 3];
        #pragma unroll
        for (int o = 16; o > 0; o >>= 1) {
            l0 += __shfl_xor(l0, o);
            l1 += __shfl_xor(l1, o);
        }
        if (lane == 0) {
            l0 += P[P_CLSB];
            l1 += P[P_CLSB + 1];
            if (flag[0]) {
                ((float2*)outp)[node] = make_float2(l0, l1);
            } else {
                ((u32*)outp)[node] = (u32)f2bf(l0) | ((u32)f2bf(l1) << 16);
            }
        }
    }
}

// ---------------------------------------------------------------------------
extern "C" void kernel_launch(void* const* d_in, const int* in_sizes, int n_in,
                              void* d_out, int out_size, void* d_ws, size_t ws_size,
                              hipStream_t stream)
{
    const void* x    = d_in[0];
    const int*  ei   = (const int*)d_in[1];
    const void* et   = d_in[2];
    const void* l1w  = d_in[3];
    const void* l1b  = d_in[4];
    const void* a1w  = d_in[5];
    const void* a1b  = d_in[6];
    const void* t1w  = d_in[7];
    const void* t1b  = d_in[8];
    const void* l2w  = d_in[9];
    const void* l2b  = d_in[10];
    const void* a2w  = d_in[11];
    const void* a2b  = d_in[12];
    const void* t2w  = d_in[13];
    const void* t2b  = d_in[14];
    const void* clsw = d_in[15];
    const void* clsb = d_in[16];

    const int N = in_sizes[0] / 128;
    const int E = in_sizes[2];

    char* ws = (char*)d_ws;
    size_t off = 0;
    auto A = [&](size_t bytes) -> char* {
        char* p = ws + off;
        off = (off + bytes + 255) & ~(size_t)255;
        return p;
    };
    int*   flag  = (int*)A(256);
    float* P     = (float*)A(P_TOT * 4);
    u32*   h1b   = (u32*)A((size_t)N * 32 * 4);    // bf16-packed h1; reused as h2
    float* hag   = (float*)A((size_t)N * 64 * 4);  // f32 aggregated (gemm2 input)
    float* si1   = (float*)A((size_t)N * 4);
    float* sj1   = (float*)A((size_t)N * 4);
    float* si2   = (float*)A((size_t)N * 4);
    float* sj2   = (float*)A((size_t)N * 4);
    float* alpha = (float*)A((size_t)E * 4);       // alpha1 then alpha2
    float* td2   = (float*)A((size_t)E * 4);
    int*   deg   = (int*)A((size_t)2 * N * 4);     // deg[N] then cursor[N]
    int*   cursor = deg + N;
    int*   offs  = (int*)A((size_t)(N + 1) * 4);
    int*   bsum  = (int*)A(512 * 4);
    int2*  csr2  = (int2*)A((size_t)E * 8);
    (void)ws_size; (void)n_in; (void)out_size;

    hipMemsetAsync(deg, 0, (size_t)2 * N * 4, stream);

    detect_dtype<<<1, 256, 0, stream>>>((const u32*)x, 4096, flag);

    prep_params<<<32, 256, 0, stream>>>(l1w, l1b, a1w, a1b, t1w, t1b,
                                        l2w, l2b, a2w, a2b, t2w, t2b,
                                        clsw, clsb, flag, P);

    node_gemm<128, true><<<(N + 63) / 64, 256, 0, stream>>>(
        x, P, P_W1, P_B1, P_A1W, flag, h1b, si1, sj1, N);

    edge_pass1<<<(E + 255) / 256, 256, 0, stream>>>(
        ei, et, si1, sj1, P, flag, alpha, td2, deg, E);

    int NB = (N + 255) / 256;
    scan_block_sums<<<NB, 256, 0, stream>>>(deg, bsum, N);
    scan_bsum<<<1, 512, 0, stream>>>(bsum, NB);
    scan_final<<<NB, 256, 0, stream>>>(deg, bsum, offs, N);

    scatter_edges<<<(E + 255) / 256, 256, 0, stream>>>(ei, offs, cursor, csr2, E);

    aggregate<0><<<(N + 3) / 4, 256, 0, stream>>>(
        offs, csr2, alpha, h1b, hag, nullptr, P, flag, N);

    node_gemm<64, false><<<(N + 63) / 64, 256, 0, stream>>>(
        hag, P, P_W2, P_B2, P_A2W, flag, h1b, si2, sj2, N);

    edge_pass2<<<(E + 255) / 256, 256, 0, stream>>>(
        ei, si2, sj2, td2, P, alpha, E);

    aggregate<1><<<(N + 3) / 4, 256, 0, stream>>>(
        offs, csr2, alpha, h1b, nullptr, d_out, P, flag, N);
}

// Round 6
// 450.896 us; speedup vs baseline: 1.9457x; 1.1358x over previous
//
#include <hip/hip_runtime.h>

typedef unsigned short u16;
typedef unsigned int u32;

__device__ __forceinline__ float bf2f(u16 u) {
    return __uint_as_float(((u32)u) << 16);
}
__device__ __forceinline__ u16 f2bf(float f) {
    u32 u = __float_as_uint(f);
    u32 r = (u + 0x7fffu + ((u >> 16) & 1u)) >> 16;
    return (u16)r;
}
__device__ __forceinline__ float ldf(const void* p, int i, int isf32) {
    return isf32 ? ((const float*)p)[i] : bf2f(((const u16*)p)[i]);
}

// ---- canonical f32 param block offsets (in floats) ----
#define P_W1   0        // 128x64
#define P_W2   8192     // 64x64
#define P_B1   12288    // 64
#define P_B2   12352    // 64
#define P_A1W  12416    // 144
#define P_A1B  12560    // 1
#define P_T1W  12561    // 16
#define P_T1B  12577    // 16
#define P_A2W  12593    // 144
#define P_A2B  12737    // 1
#define P_T2W  12738    // 16
#define P_T2B  12754    // 16
#define P_CLSW 12770    // 128 (64x2)
#define P_CLSB 12898    // 2
#define P_TOT  12900

#define NBKT 512        // dst buckets
#define SH   8          // shards (~XCD via blockIdx&7 round-robin heuristic)
#define SCAP 768        // per (shard,bucket) staging capacity; mean 391, +19 sigma
#define CAP  512        // aggregate per-node LDS cache

// ---------------------------------------------------------------------------
// Detect f32 vs bf16 storage of float tensors (round-1 notes).
// ---------------------------------------------------------------------------
__global__ __launch_bounds__(256) void detect_dtype(
    const u32* __restrict__ xw, int nwords, int* __restrict__ flag)
{
    __shared__ int sbad;
    if (threadIdx.x == 0) sbad = 0;
    __syncthreads();
    int bad = 0;
    for (int i = threadIdx.x; i < nwords; i += 256) {
        u32 w = xw[i];
        int ea = (w >> 7) & 0xff;
        if (ea >= 0xF0) bad = 1;
    }
    if (bad) sbad = 1;
    __syncthreads();
    if (threadIdx.x == 0) flag[0] = sbad;
}

// ---------------------------------------------------------------------------
// Convert all small parameter tensors into one f32 param block.
// ---------------------------------------------------------------------------
__global__ __launch_bounds__(256) void prep_params(
    const void* l1w, const void* l1b, const void* a1w, const void* a1b,
    const void* t1w, const void* t1b, const void* l2w, const void* l2b,
    const void* a2w, const void* a2b, const void* t2w, const void* t2b,
    const void* clsw, const void* clsb,
    const int* __restrict__ flag, float* __restrict__ P)
{
    const int f = flag[0];
    const int t = blockIdx.x * 256 + threadIdx.x;
    const int stride = gridDim.x * 256;
#define SEG(src, off, cnt) for (int i = t; i < (cnt); i += stride) P[(off) + i] = ldf(src, i, f)
    SEG(l1w, P_W1, 8192);
    SEG(l2w, P_W2, 4096);
    SEG(l1b, P_B1, 64);
    SEG(l2b, P_B2, 64);
    SEG(a1w, P_A1W, 144);
    SEG(a1b, P_A1B, 1);
    SEG(t1w, P_T1W, 16);
    SEG(t1b, P_T1B, 16);
    SEG(a2w, P_A2W, 144);
    SEG(a2b, P_A2B, 1);
    SEG(t2w, P_T2W, 16);
    SEG(t2b, P_T2B, 16);
    SEG(clsw, P_CLSW, 128);
    SEG(clsb, P_CLSB, 2);
#undef SEG
}

// ---------------------------------------------------------------------------
// Node transform as tiled GEMM (unchanged from round 5, passing):
// h[N,64] = x @ W + b packed bf16; fused si/sj attention scalars.
// ---------------------------------------------------------------------------
template<int K, bool DYNAMIC>
__global__ __launch_bounds__(256) void node_gemm(
    const void* __restrict__ xin, const float* __restrict__ P,
    int WOFF, int BOFF, int AOFF, const int* __restrict__ flag,
    u32* __restrict__ houtb, float* __restrict__ si, float* __restrict__ sj,
    int nnodes)
{
    __shared__ float Ws[K * 64];
    __shared__ float As[32][66];
    const int t = threadIdx.x;
    const int tx = t & 15;
    const int ty = t >> 4;
    const int base = blockIdx.x * 64;
    const bool xf32 = DYNAMIC ? (flag[0] != 0) : true;

    for (int i = t * 4; i < K * 64; i += 1024)
        *(float4*)&Ws[i] = *(const float4*)&P[WOFF + i];

    float acc[4][4];
    #pragma unroll
    for (int r = 0; r < 4; ++r)
        #pragma unroll
        for (int c = 0; c < 4; ++c) acc[r][c] = 0.f;

    for (int k0 = 0; k0 < K; k0 += 32) {
        __syncthreads();
        if (!DYNAMIC || xf32) {
            #pragma unroll
            for (int it = 0; it < 2; ++it) {
                int idx = t + it * 256;
                int row = idx >> 3, cq = (idx & 7) * 4;
                float4 v = make_float4(0.f, 0.f, 0.f, 0.f);
                if (base + row < nnodes)
                    v = *(const float4*)&((const float*)xin)[(size_t)(base + row) * K + k0 + cq];
                As[cq + 0][row] = v.x; As[cq + 1][row] = v.y;
                As[cq + 2][row] = v.z; As[cq + 3][row] = v.w;
            }
        } else {
            int row = t >> 2, q = (t & 3) * 8;
            uint4 v = make_uint4(0u, 0u, 0u, 0u);
            if (base + row < nnodes)
                v = *(const uint4*)&((const u16*)xin)[(size_t)(base + row) * K + k0 + q];
            As[q + 0][row] = bf2f((u16)(v.x & 0xffffu));
            As[q + 1][row] = bf2f((u16)(v.x >> 16));
            As[q + 2][row] = bf2f((u16)(v.y & 0xffffu));
            As[q + 3][row] = bf2f((u16)(v.y >> 16));
            As[q + 4][row] = bf2f((u16)(v.z & 0xffffu));
            As[q + 5][row] = bf2f((u16)(v.z >> 16));
            As[q + 6][row] = bf2f((u16)(v.w & 0xffffu));
            As[q + 7][row] = bf2f((u16)(v.w >> 16));
        }
        __syncthreads();

        #pragma unroll
        for (int k = 0; k < 32; ++k) {
            float2 a01 = *(float2*)&As[k][ty * 4];
            float2 a23 = *(float2*)&As[k][ty * 4 + 2];
            float4 b = *(float4*)&Ws[(k0 + k) * 64 + tx * 4];
            float a[4] = { a01.x, a01.y, a23.x, a23.y };
            float bb[4] = { b.x, b.y, b.z, b.w };
            #pragma unroll
            for (int r = 0; r < 4; ++r)
                #pragma unroll
                for (int c = 0; c < 4; ++c)
                    acc[r][c] = fmaf(a[r], bb[c], acc[r][c]);
        }
    }

    #pragma unroll
    for (int c = 0; c < 4; ++c) {
        float bc = P[BOFF + tx * 4 + c];
        #pragma unroll
        for (int r = 0; r < 4; ++r) acc[r][c] += bc;
    }

    float vi[4], vj[4];
    #pragma unroll
    for (int r = 0; r < 4; ++r) {
        float a_i = 0.f, a_j = 0.f;
        #pragma unroll
        for (int c = 0; c < 4; ++c) {
            a_i = fmaf(acc[r][c], P[AOFF + tx * 4 + c], a_i);
            a_j = fmaf(acc[r][c], P[AOFF + 64 + tx * 4 + c], a_j);
        }
        vi[r] = a_i; vj[r] = a_j;
    }
    #pragma unroll
    for (int o = 1; o < 16; o <<= 1) {
        #pragma unroll
        for (int r = 0; r < 4; ++r) {
            vi[r] += __shfl_xor(vi[r], o);
            vj[r] += __shfl_xor(vj[r], o);
        }
    }

    #pragma unroll
    for (int r = 0; r < 4; ++r) {
        int node = base + ty * 4 + r;
        if (node < nnodes) {
            u32 w0 = (u32)f2bf(acc[r][0]) | ((u32)f2bf(acc[r][1]) << 16);
            u32 w1 = (u32)f2bf(acc[r][2]) | ((u32)f2bf(acc[r][3]) << 16);
            *(uint2*)&houtb[(size_t)node * 32 + tx * 2] = make_uint2(w0, w1);
            if (tx == 0) { si[node] = vi[r]; sj[node] = vj[r]; }
        }
    }
}

// ---------------------------------------------------------------------------
// Stage edges into (bucket, shard) segments. shard = blockIdx&7 ~ XCD, so a
// segment's tail line stays in ONE XCD's L2 -> dense writeback.
// Payload (src, dst, t_bits) int4.
// ---------------------------------------------------------------------------
__global__ __launch_bounds__(256) void stage_edges(
    const int* __restrict__ ei, const void* __restrict__ et,
    const int* __restrict__ flag, int4* __restrict__ staging,
    int* __restrict__ cur8, int E, int npb)
{
    int e = blockIdx.x * 256 + threadIdx.x;
    if (e >= E) return;
    int s = ei[e], d = ei[E + e];
    float tt = ldf(et, e, flag[0]);
    int b = d / npb;
    int sh = blockIdx.x & 7;
    int p = atomicAdd(&cur8[sh * NBKT + b], 1);
    if (p < SCAP)
        staging[((size_t)(sh * NBKT + b)) * SCAP + p] =
            make_int4(s, d, __float_as_int(tt), 0);
}

// ---------------------------------------------------------------------------
// Exclusive scan of per-bucket totals (1 block, 512 threads).
// ---------------------------------------------------------------------------
__global__ __launch_bounds__(512) void bucket_scan(
    const int* __restrict__ cur8, int* __restrict__ bscan,
    int* __restrict__ offs, int N)
{
    __shared__ int s[512];
    int b = threadIdx.x;
    int tot = 0;
    #pragma unroll
    for (int sh = 0; sh < SH; ++sh) tot += min(cur8[sh * NBKT + b], SCAP);
    s[b] = tot;
    __syncthreads();
    for (int off = 1; off < 512; off <<= 1) {
        int x = (b >= off) ? s[b - off] : 0;
        __syncthreads();
        s[b] += x;
        __syncthreads();
    }
    bscan[b] = s[b] - tot;
    if (b == 511) offs[N] = s[511];
}

// ---------------------------------------------------------------------------
// Bin: one block per bucket. Pass 1 counts per-node, LDS scan -> offs and
// cursors, pass 2 places (src, t) into csr2 (writes land in the bucket's
// contiguous ~25 KB window -> L2-resident -> dense writeback).
// ---------------------------------------------------------------------------
__global__ __launch_bounds__(256) void bin_edges(
    const int4* __restrict__ staging, const int* __restrict__ cur8,
    const int* __restrict__ bscan, int* __restrict__ offs,
    int2* __restrict__ csr2, int N, int npb)
{
    __shared__ int cnt[256];
    __shared__ int loc[256];
    const int b = blockIdx.x;
    const int nstart = b * npb;
    const int t = threadIdx.x;
    cnt[t] = 0;
    __syncthreads();
    int segc[SH];
    #pragma unroll
    for (int sh = 0; sh < SH; ++sh) {
        segc[sh] = min(cur8[sh * NBKT + b], SCAP);
        const int4* seg = staging + ((size_t)(sh * NBKT + b)) * SCAP;
        for (int i = t; i < segc[sh]; i += 256)
            atomicAdd(&cnt[seg[i].y - nstart], 1);
    }
    __syncthreads();
    int v = cnt[t];
    loc[t] = v;
    __syncthreads();
    for (int off = 1; off < 256; off <<= 1) {
        int x = (t >= off) ? loc[t - off] : 0;
        __syncthreads();
        loc[t] += x;
        __syncthreads();
    }
    const int cur = bscan[b] + loc[t] - v;   // exclusive + bucket base
    if (t < npb && nstart + t < N) offs[nstart + t] = cur;
    cnt[t] = cur;
    __syncthreads();
    #pragma unroll
    for (int sh = 0; sh < SH; ++sh) {
        const int4* seg = staging + ((size_t)(sh * NBKT + b)) * SCAP;
        for (int i = t; i < segc[sh]; i += 256) {
            int4 v4 = seg[i];
            int slot = atomicAdd(&cnt[v4.y - nstart], 1);
            csr2[slot] = make_int2(v4.x, v4.z);
        }
    }
}

// ---------------------------------------------------------------------------
// Aggregate: wave per node. Alpha recomputed in-kernel from (src,t) CSR:
// a = si[node] + sj[src] + 16-term sin dot + bias, leaky. LDS cache of
// (src, alpha). Phase B: half-wave per edge, 4 row-loads in flight.
// MODE 0 -> relu f32 rows; MODE 1 -> classifier to d_out.
// ---------------------------------------------------------------------------
template<int MODE>
__global__ __launch_bounds__(256) void aggregate(
    const int* __restrict__ offs, const int2* __restrict__ csr2,
    const u32* __restrict__ hb,
    const float* __restrict__ si, const float* __restrict__ sjv,
    const float* __restrict__ P, int TW, int TB, int AWT, int AB,
    float* __restrict__ hout, void* __restrict__ outp,
    const int* __restrict__ flag, int n)
{
    __shared__ int2 cache[4][CAP];
    const int wave = threadIdx.x >> 6, lane = threadIdx.x & 63;
    const int node = blockIdx.x * 4 + wave;
    const bool active = node < n;
    int beg = 0, end = 0;
    if (active) { beg = offs[node]; end = offs[node + 1]; }
    const int deg = end - beg;
    int2* cw = cache[wave];
    const float sii = active ? si[node] : 0.f;
    const float ab = P[AB];

    float twv[16], tbv[16], awv[16];
    #pragma unroll
    for (int k = 0; k < 16; ++k) {
        twv[k] = P[TW + k]; tbv[k] = P[TB + k]; awv[k] = P[AWT + k];
    }

    auto ealpha = [&](int idx) -> int2 {
        int2 st = csr2[beg + idx];
        float tt = __int_as_float(st.y);
        float td = 0.f;
        #pragma unroll
        for (int k = 0; k < 16; ++k)
            td += __sinf(fmaf(tt, twv[k], tbv[k])) * awv[k];
        float a = sii + sjv[st.x] + td + ab;
        a = (a > 0.f) ? a : 0.01f * a;
        return make_int2(st.x, __float_as_int(a));
    };

    // phase A: compute alpha once per edge, fill LDS cache, wave-max
    float m = -3.4e38f;
    for (int idx = lane; idx < deg; idx += 64) {
        int2 sa = ealpha(idx);
        if (idx < CAP) cw[idx] = sa;
        m = fmaxf(m, __int_as_float(sa.y));
    }
    #pragma unroll
    for (int o = 32; o > 0; o >>= 1) m = fmaxf(m, __shfl_xor(m, o));
    __syncthreads();

    // softmax denominator
    float ssum = 0.f;
    for (int idx = lane; idx < deg; idx += 64) {
        float a = (idx < CAP) ? __int_as_float(cw[idx].y)
                              : __int_as_float(ealpha(idx).y);
        ssum += __expf(a - m);
    }
    #pragma unroll
    for (int o = 32; o > 0; o >>= 1) ssum += __shfl_xor(ssum, o);

    // phase B: half-wave per edge; lane covers features 2*fl, 2*fl+1
    const int half = lane >> 5;
    const int fl = lane & 31;
    float ax = 0.f, ay = 0.f;
    int j0 = 0;
    if (deg <= CAP) {
        for (; j0 + 8 <= deg; j0 += 8) {
            int2 s0 = cw[j0 + 0 + half];
            int2 s1 = cw[j0 + 2 + half];
            int2 s2 = cw[j0 + 4 + half];
            int2 s3 = cw[j0 + 6 + half];
            u32 p0 = hb[(size_t)s0.x * 32 + fl];
            u32 p1 = hb[(size_t)s1.x * 32 + fl];
            u32 p2 = hb[(size_t)s2.x * 32 + fl];
            u32 p3 = hb[(size_t)s3.x * 32 + fl];
            float e0 = __expf(__int_as_float(s0.y) - m);
            float e1 = __expf(__int_as_float(s1.y) - m);
            float e2 = __expf(__int_as_float(s2.y) - m);
            float e3 = __expf(__int_as_float(s3.y) - m);
            ax = fmaf(e0, bf2f((u16)(p0 & 0xffffu)), ax);
            ay = fmaf(e0, bf2f((u16)(p0 >> 16)), ay);
            ax = fmaf(e1, bf2f((u16)(p1 & 0xffffu)), ax);
            ay = fmaf(e1, bf2f((u16)(p1 >> 16)), ay);
            ax = fmaf(e2, bf2f((u16)(p2 & 0xffffu)), ax);
            ay = fmaf(e2, bf2f((u16)(p2 >> 16)), ay);
            ax = fmaf(e3, bf2f((u16)(p3 & 0xffffu)), ax);
            ay = fmaf(e3, bf2f((u16)(p3 >> 16)), ay);
        }
    }
    for (; j0 < deg; j0 += 2) {
        int j = j0 + half;
        float ex = 0.f;
        int src = 0;
        if (j < deg) {
            int2 sa = (j < CAP) ? cw[j] : ealpha(j);
            src = sa.x;
            ex = __expf(__int_as_float(sa.y) - m);
        }
        u32 pk = hb[(size_t)src * 32 + fl];
        ax = fmaf(ex, bf2f((u16)(pk & 0xffffu)), ax);
        ay = fmaf(ex, bf2f((u16)(pk >> 16)), ay);
    }
    ax += __shfl_xor(ax, 32);
    ay += __shfl_xor(ay, 32);

    if (!active) return;
    float inv = 1.0f / (ssum + 1e-16f);

    if (MODE == 0) {
        if (lane < 32) {
            float2 v = make_float2(fmaxf(ax * inv, 0.f), fmaxf(ay * inv, 0.f));
            *(float2*)&hout[(size_t)node * 64 + fl * 2] = v;
        }
    } else {
        float r0 = ax * inv, r1 = ay * inv;
        float l0 = r0 * P[P_CLSW + 4 * fl]     + r1 * P[P_CLSW + 4 * fl + 2];
        float l1 = r0 * P[P_CLSW + 4 * fl + 1] + r1 * P[P_CLSW + 4 * fl + 3];
        #pragma unroll
        for (int o = 16; o > 0; o >>= 1) {
            l0 += __shfl_xor(l0, o);
            l1 += __shfl_xor(l1, o);
        }
        if (lane == 0) {
            l0 += P[P_CLSB];
            l1 += P[P_CLSB + 1];
            if (flag[0]) {
                ((float2*)outp)[node] = make_float2(l0, l1);
            } else {
                ((u32*)outp)[node] = (u32)f2bf(l0) | ((u32)f2bf(l1) << 16);
            }
        }
    }
}

// ---------------------------------------------------------------------------
extern "C" void kernel_launch(void* const* d_in, const int* in_sizes, int n_in,
                              void* d_out, int out_size, void* d_ws, size_t ws_size,
                              hipStream_t stream)
{
    const void* x    = d_in[0];
    const int*  ei   = (const int*)d_in[1];
    const void* et   = d_in[2];
    const void* l1w  = d_in[3];
    const void* l1b  = d_in[4];
    const void* a1w  = d_in[5];
    const void* a1b  = d_in[6];
    const void* t1w  = d_in[7];
    const void* t1b  = d_in[8];
    const void* l2w  = d_in[9];
    const void* l2b  = d_in[10];
    const void* a2w  = d_in[11];
    const void* a2b  = d_in[12];
    const void* t2w  = d_in[13];
    const void* t2b  = d_in[14];
    const void* clsw = d_in[15];
    const void* clsb = d_in[16];

    const int N = in_sizes[0] / 128;
    const int E = in_sizes[2];
    const int npb = (N + NBKT - 1) / NBKT;   // nodes per bucket (196)

    char* ws = (char*)d_ws;
    size_t off = 0;
    auto A = [&](size_t bytes) -> char* {
        char* p = ws + off;
        off = (off + bytes + 255) & ~(size_t)255;
        return p;
    };
    int*   flag  = (int*)A(256);
    float* P     = (float*)A(P_TOT * 4);
    u32*   h1b   = (u32*)A((size_t)N * 32 * 4);    // bf16-packed h1; reused as h2
    float* si1   = (float*)A((size_t)N * 4);
    float* sj1   = (float*)A((size_t)N * 4);
    float* si2   = (float*)A((size_t)N * 4);
    float* sj2   = (float*)A((size_t)N * 4);
    int*   cur8  = (int*)A((size_t)SH * NBKT * 4);
    int*   bscan = (int*)A((size_t)NBKT * 4);
    int*   offs  = (int*)A((size_t)(N + 1) * 4);
    int2*  csr2  = (int2*)A((size_t)E * 8);
    char*  unionr = A((size_t)SH * NBKT * SCAP * 16);  // staging, then hag
    int4*  staging = (int4*)unionr;
    float* hag     = (float*)unionr;                    // agg0 output (after bin)
    (void)ws_size; (void)n_in; (void)out_size;

    hipMemsetAsync(cur8, 0, (size_t)SH * NBKT * 4, stream);

    detect_dtype<<<1, 256, 0, stream>>>((const u32*)x, 4096, flag);

    prep_params<<<32, 256, 0, stream>>>(l1w, l1b, a1w, a1b, t1w, t1b,
                                        l2w, l2b, a2w, a2b, t2w, t2b,
                                        clsw, clsb, flag, P);

    node_gemm<128, true><<<(N + 63) / 64, 256, 0, stream>>>(
        x, P, P_W1, P_B1, P_A1W, flag, h1b, si1, sj1, N);

    stage_edges<<<(E + 255) / 256, 256, 0, stream>>>(
        ei, et, flag, staging, cur8, E, npb);

    bucket_scan<<<1, 512, 0, stream>>>(cur8, bscan, offs, N);

    bin_edges<<<NBKT, 256, 0, stream>>>(
        staging, cur8, bscan, offs, csr2, N, npb);

    aggregate<0><<<(N + 3) / 4, 256, 0, stream>>>(
        offs, csr2, h1b, si1, sj1, P, P_T1W, P_T1B, P_A1W + 128, P_A1B,
        hag, nullptr, flag, N);

    node_gemm<64, false><<<(N + 63) / 64, 256, 0, stream>>>(
        hag, P, P_W2, P_B2, P_A2W, flag, h1b, si2, sj2, N);

    aggregate<1><<<(N + 3) / 4, 256, 0, stream>>>(
        offs, csr2, h1b, si2, sj2, P, P_T2W, P_T2B, P_A2W + 128, P_A2B,
        nullptr, d_out, flag, N);
}

// Round 7
// 444.181 us; speedup vs baseline: 1.9751x; 1.0151x over previous
//
#include <hip/hip_runtime.h>

typedef unsigned short u16;
typedef unsigned int u32;

__device__ __forceinline__ float bf2f(u16 u) {
    return __uint_as_float(((u32)u) << 16);
}
__device__ __forceinline__ u16 f2bf(float f) {
    u32 u = __float_as_uint(f);
    u32 r = (u + 0x7fffu + ((u >> 16) & 1u)) >> 16;
    return (u16)r;
}
__device__ __forceinline__ float ldf(const void* p, int i, int isf32) {
    return isf32 ? ((const float*)p)[i] : bf2f(((const u16*)p)[i]);
}
// real XCD id (0-7): hwreg(HW_REG_XCC_ID=20, offset 0, size 4) -> imm 6164
__device__ __forceinline__ int xcd_id() {
    return __builtin_amdgcn_s_getreg((3 << 11) | (0 << 6) | 20) & 7;
}

// ---- canonical f32 param block offsets (in floats) ----
#define P_W1   0        // 128x64
#define P_W2   8192     // 64x64
#define P_B1   12288    // 64
#define P_B2   12352    // 64
#define P_A1W  12416    // 144
#define P_A1B  12560    // 1
#define P_T1W  12561    // 16
#define P_T1B  12577    // 16
#define P_A2W  12593    // 144
#define P_A2B  12737    // 1
#define P_T2W  12738    // 16
#define P_T2B  12754    // 16
#define P_CLSW 12770    // 128 (64x2)
#define P_CLSB 12898    // 2
#define P_TOT  12900

#define NBKT 512        // dst buckets
#define SH   8          // shards = real XCDs
#define SCAP 640        // per (xcd,bucket) staging cap; mean 390, +12 sigma
#define OVFCAP 65536    // overflow list (expected 0 used)
#define CAP  512        // aggregate per-node LDS cache

// ---------------------------------------------------------------------------
// Detect f32 vs bf16 storage of float tensors (round-1 notes).
// ---------------------------------------------------------------------------
__global__ __launch_bounds__(256) void detect_dtype(
    const u32* __restrict__ xw, int nwords, int* __restrict__ flag)
{
    __shared__ int sbad;
    if (threadIdx.x == 0) sbad = 0;
    __syncthreads();
    int bad = 0;
    for (int i = threadIdx.x; i < nwords; i += 256) {
        u32 w = xw[i];
        int ea = (w >> 7) & 0xff;
        if (ea >= 0xF0) bad = 1;
    }
    if (bad) sbad = 1;
    __syncthreads();
    if (threadIdx.x == 0) flag[0] = sbad;
}

// ---------------------------------------------------------------------------
// Convert all small parameter tensors into one f32 param block.
// ---------------------------------------------------------------------------
__global__ __launch_bounds__(256) void prep_params(
    const void* l1w, const void* l1b, const void* a1w, const void* a1b,
    const void* t1w, const void* t1b, const void* l2w, const void* l2b,
    const void* a2w, const void* a2b, const void* t2w, const void* t2b,
    const void* clsw, const void* clsb,
    const int* __restrict__ flag, float* __restrict__ P)
{
    const int f = flag[0];
    const int t = blockIdx.x * 256 + threadIdx.x;
    const int stride = gridDim.x * 256;
#define SEG(src, off, cnt) for (int i = t; i < (cnt); i += stride) P[(off) + i] = ldf(src, i, f)
    SEG(l1w, P_W1, 8192);
    SEG(l2w, P_W2, 4096);
    SEG(l1b, P_B1, 64);
    SEG(l2b, P_B2, 64);
    SEG(a1w, P_A1W, 144);
    SEG(a1b, P_A1B, 1);
    SEG(t1w, P_T1W, 16);
    SEG(t1b, P_T1B, 16);
    SEG(a2w, P_A2W, 144);
    SEG(a2b, P_A2B, 1);
    SEG(t2w, P_T2W, 16);
    SEG(t2b, P_T2B, 16);
    SEG(clsw, P_CLSW, 128);
    SEG(clsb, P_CLSB, 2);
#undef SEG
}

// ---------------------------------------------------------------------------
// Node transform as tiled GEMM (unchanged, passing):
// h[N,64] = x @ W + b packed bf16; fused si/sj attention scalars.
// ---------------------------------------------------------------------------
template<int K, bool DYNAMIC>
__global__ __launch_bounds__(256) void node_gemm(
    const void* __restrict__ xin, const float* __restrict__ P,
    int WOFF, int BOFF, int AOFF, const int* __restrict__ flag,
    u32* __restrict__ houtb, float* __restrict__ si, float* __restrict__ sj,
    int nnodes)
{
    __shared__ float Ws[K * 64];
    __shared__ float As[32][66];
    const int t = threadIdx.x;
    const int tx = t & 15;
    const int ty = t >> 4;
    const int base = blockIdx.x * 64;
    const bool xf32 = DYNAMIC ? (flag[0] != 0) : true;

    for (int i = t * 4; i < K * 64; i += 1024)
        *(float4*)&Ws[i] = *(const float4*)&P[WOFF + i];

    float acc[4][4];
    #pragma unroll
    for (int r = 0; r < 4; ++r)
        #pragma unroll
        for (int c = 0; c < 4; ++c) acc[r][c] = 0.f;

    for (int k0 = 0; k0 < K; k0 += 32) {
        __syncthreads();
        if (!DYNAMIC || xf32) {
            #pragma unroll
            for (int it = 0; it < 2; ++it) {
                int idx = t + it * 256;
                int row = idx >> 3, cq = (idx & 7) * 4;
                float4 v = make_float4(0.f, 0.f, 0.f, 0.f);
                if (base + row < nnodes)
                    v = *(const float4*)&((const float*)xin)[(size_t)(base + row) * K + k0 + cq];
                As[cq + 0][row] = v.x; As[cq + 1][row] = v.y;
                As[cq + 2][row] = v.z; As[cq + 3][row] = v.w;
            }
        } else {
            int row = t >> 2, q = (t & 3) * 8;
            uint4 v = make_uint4(0u, 0u, 0u, 0u);
            if (base + row < nnodes)
                v = *(const uint4*)&((const u16*)xin)[(size_t)(base + row) * K + k0 + q];
            As[q + 0][row] = bf2f((u16)(v.x & 0xffffu));
            As[q + 1][row] = bf2f((u16)(v.x >> 16));
            As[q + 2][row] = bf2f((u16)(v.y & 0xffffu));
            As[q + 3][row] = bf2f((u16)(v.y >> 16));
            As[q + 4][row] = bf2f((u16)(v.z & 0xffffu));
            As[q + 5][row] = bf2f((u16)(v.z >> 16));
            As[q + 6][row] = bf2f((u16)(v.w & 0xffffu));
            As[q + 7][row] = bf2f((u16)(v.w >> 16));
        }
        __syncthreads();

        #pragma unroll
        for (int k = 0; k < 32; ++k) {
            float2 a01 = *(float2*)&As[k][ty * 4];
            float2 a23 = *(float2*)&As[k][ty * 4 + 2];
            float4 b = *(float4*)&Ws[(k0 + k) * 64 + tx * 4];
            float a[4] = { a01.x, a01.y, a23.x, a23.y };
            float bb[4] = { b.x, b.y, b.z, b.w };
            #pragma unroll
            for (int r = 0; r < 4; ++r)
                #pragma unroll
                for (int c = 0; c < 4; ++c)
                    acc[r][c] = fmaf(a[r], bb[c], acc[r][c]);
        }
    }

    #pragma unroll
    for (int c = 0; c < 4; ++c) {
        float bc = P[BOFF + tx * 4 + c];
        #pragma unroll
        for (int r = 0; r < 4; ++r) acc[r][c] += bc;
    }

    float vi[4], vj[4];
    #pragma unroll
    for (int r = 0; r < 4; ++r) {
        float a_i = 0.f, a_j = 0.f;
        #pragma unroll
        for (int c = 0; c < 4; ++c) {
            a_i = fmaf(acc[r][c], P[AOFF + tx * 4 + c], a_i);
            a_j = fmaf(acc[r][c], P[AOFF + 64 + tx * 4 + c], a_j);
        }
        vi[r] = a_i; vj[r] = a_j;
    }
    #pragma unroll
    for (int o = 1; o < 16; o <<= 1) {
        #pragma unroll
        for (int r = 0; r < 4; ++r) {
            vi[r] += __shfl_xor(vi[r], o);
            vj[r] += __shfl_xor(vj[r], o);
        }
    }

    #pragma unroll
    for (int r = 0; r < 4; ++r) {
        int node = base + ty * 4 + r;
        if (node < nnodes) {
            u32 w0 = (u32)f2bf(acc[r][0]) | ((u32)f2bf(acc[r][1]) << 16);
            u32 w1 = (u32)f2bf(acc[r][2]) | ((u32)f2bf(acc[r][3]) << 16);
            *(uint2*)&houtb[(size_t)node * 32 + tx * 2] = make_uint2(w0, w1);
            if (tx == 0) { si[node] = vi[r]; sj[node] = vj[r]; }
        }
    }
}

// ---------------------------------------------------------------------------
// Stage edges into (bucket, REAL-XCD) segments; payload int2
// (src | local_dst<<17, t_bits). Segment tail lines are single-XCD-owned
// -> fill in that XCD's L2 -> dense writeback. Overflow -> global list.
// ---------------------------------------------------------------------------
__global__ __launch_bounds__(256) void stage_edges(
    const int* __restrict__ ei, const void* __restrict__ et,
    const int* __restrict__ flag, int2* __restrict__ staging,
    int* __restrict__ cur8, int* __restrict__ ovfcnt,
    int4* __restrict__ ovf, int E, int npb)
{
    int e = blockIdx.x * 256 + threadIdx.x;
    if (e >= E) return;
    int s = ei[e], d = ei[E + e];
    float tt = ldf(et, e, flag[0]);
    int b = d / npb;
    int ldst = d - b * npb;
    int w0 = s | (ldst << 17);
    int sh = xcd_id();
    int p = atomicAdd(&cur8[sh * NBKT + b], 1);
    if (p < SCAP) {
        staging[((size_t)(sh * NBKT + b)) * SCAP + p] =
            make_int2(w0, __float_as_int(tt));
    } else {
        int q = atomicAdd(ovfcnt, 1);
        if (q < OVFCAP) ovf[q] = make_int4(w0, __float_as_int(tt), b, 0);
    }
}

// ---------------------------------------------------------------------------
// Exclusive scan of per-bucket totals (1 block, 512 threads) + overflow.
// ---------------------------------------------------------------------------
__global__ __launch_bounds__(512) void bucket_scan(
    const int* __restrict__ cur8, const int* __restrict__ ovfcnt,
    const int4* __restrict__ ovf, int* __restrict__ bscan,
    int* __restrict__ offs, int N)
{
    __shared__ int s[512];
    int b = threadIdx.x;
    int tot = 0;
    #pragma unroll
    for (int sh = 0; sh < SH; ++sh) tot += min(cur8[sh * NBKT + b], SCAP);
    s[b] = tot;
    __syncthreads();
    int novf = min(ovfcnt[0], OVFCAP);
    for (int i = b; i < novf; i += 512) atomicAdd(&s[ovf[i].z], 1);
    __syncthreads();
    tot = s[b];
    __syncthreads();
    for (int off = 1; off < 512; off <<= 1) {
        int x = (b >= off) ? s[b - off] : 0;
        __syncthreads();
        s[b] += x;
        __syncthreads();
    }
    bscan[b] = s[b] - tot;
    if (b == 511) offs[N] = s[511];
}

// ---------------------------------------------------------------------------
// Bin: one block per bucket. Pass 1: per-node LDS histogram, scan -> offs.
// Pass 2: place (src, t) into the bucket's contiguous csr2 window.
// ---------------------------------------------------------------------------
__global__ __launch_bounds__(256) void bin_edges(
    const int2* __restrict__ staging, const int* __restrict__ cur8,
    const int* __restrict__ ovfcnt, const int4* __restrict__ ovf,
    const int* __restrict__ bscan, int* __restrict__ offs,
    int2* __restrict__ csr2, int N, int npb)
{
    __shared__ int cnt[256];
    __shared__ int loc[256];
    const int b = blockIdx.x;
    const int nstart = b * npb;
    const int t = threadIdx.x;
    cnt[t] = 0;
    __syncthreads();
    int segc[SH];
    const int novf = min(ovfcnt[0], OVFCAP);
    #pragma unroll
    for (int sh = 0; sh < SH; ++sh) {
        segc[sh] = min(cur8[sh * NBKT + b], SCAP);
        const int2* seg = staging + ((size_t)(sh * NBKT + b)) * SCAP;
        for (int i = t; i < segc[sh]; i += 256)
            atomicAdd(&cnt[((u32)seg[i].x) >> 17], 1);
    }
    for (int i = t; i < novf; i += 256)
        if (ovf[i].z == b) atomicAdd(&cnt[((u32)ovf[i].x) >> 17], 1);
    __syncthreads();
    int v = cnt[t];
    loc[t] = v;
    __syncthreads();
    for (int off = 1; off < 256; off <<= 1) {
        int x = (t >= off) ? loc[t - off] : 0;
        __syncthreads();
        loc[t] += x;
        __syncthreads();
    }
    const int cur = bscan[b] + loc[t] - v;   // exclusive + bucket base
    if (t < npb && nstart + t < N) offs[nstart + t] = cur;
    cnt[t] = cur;
    __syncthreads();
    #pragma unroll
    for (int sh = 0; sh < SH; ++sh) {
        const int2* seg = staging + ((size_t)(sh * NBKT + b)) * SCAP;
        for (int i = t; i < segc[sh]; i += 256) {
            int2 v2 = seg[i];
            int slot = atomicAdd(&cnt[((u32)v2.x) >> 17], 1);
            csr2[slot] = make_int2(v2.x & 0x1ffff, v2.y);
        }
    }
    for (int i = t; i < novf; i += 256) {
        int4 o = ovf[i];
        if (o.z == b) {
            int slot = atomicAdd(&cnt[((u32)o.x) >> 17], 1);
            csr2[slot] = make_int2(o.x & 0x1ffff, o.y);
        }
    }
}

// ---------------------------------------------------------------------------
// Aggregate (unchanged, passing): wave per node, alpha recomputed from
// (src,t) CSR; LDS cache; half-wave phase B with 4 loads in flight.
// ---------------------------------------------------------------------------
template<int MODE>
__global__ __launch_bounds__(256) void aggregate(
    const int* __restrict__ offs, const int2* __restrict__ csr2,
    const u32* __restrict__ hb,
    const float* __restrict__ si, const float* __restrict__ sjv,
    const float* __restrict__ P, int TW, int TB, int AWT, int AB,
    float* __restrict__ hout, void* __restrict__ outp,
    const int* __restrict__ flag, int n)
{
    __shared__ int2 cache[4][CAP];
    const int wave = threadIdx.x >> 6, lane = threadIdx.x & 63;
    const int node = blockIdx.x * 4 + wave;
    const bool active = node < n;
    int beg = 0, end = 0;
    if (active) { beg = offs[node]; end = offs[node + 1]; }
    const int deg = end - beg;
    int2* cw = cache[wave];
    const float sii = active ? si[node] : 0.f;
    const float ab = P[AB];

    float twv[16], tbv[16], awv[16];
    #pragma unroll
    for (int k = 0; k < 16; ++k) {
        twv[k] = P[TW + k]; tbv[k] = P[TB + k]; awv[k] = P[AWT + k];
    }

    auto ealpha = [&](int idx) -> int2 {
        int2 st = csr2[beg + idx];
        float tt = __int_as_float(st.y);
        float td = 0.f;
        #pragma unroll
        for (int k = 0; k < 16; ++k)
            td += __sinf(fmaf(tt, twv[k], tbv[k])) * awv[k];
        float a = sii + sjv[st.x] + td + ab;
        a = (a > 0.f) ? a : 0.01f * a;
        return make_int2(st.x, __float_as_int(a));
    };

    float m = -3.4e38f;
    for (int idx = lane; idx < deg; idx += 64) {
        int2 sa = ealpha(idx);
        if (idx < CAP) cw[idx] = sa;
        m = fmaxf(m, __int_as_float(sa.y));
    }
    #pragma unroll
    for (int o = 32; o > 0; o >>= 1) m = fmaxf(m, __shfl_xor(m, o));
    __syncthreads();

    float ssum = 0.f;
    for (int idx = lane; idx < deg; idx += 64) {
        float a = (idx < CAP) ? __int_as_float(cw[idx].y)
                              : __int_as_float(ealpha(idx).y);
        ssum += __expf(a - m);
    }
    #pragma unroll
    for (int o = 32; o > 0; o >>= 1) ssum += __shfl_xor(ssum, o);

    const int half = lane >> 5;
    const int fl = lane & 31;
    float ax = 0.f, ay = 0.f;
    int j0 = 0;
    if (deg <= CAP) {
        for (; j0 + 8 <= deg; j0 += 8) {
            int2 s0 = cw[j0 + 0 + half];
            int2 s1 = cw[j0 + 2 + half];
            int2 s2 = cw[j0 + 4 + half];
            int2 s3 = cw[j0 + 6 + half];
            u32 p0 = hb[(size_t)s0.x * 32 + fl];
            u32 p1 = hb[(size_t)s1.x * 32 + fl];
            u32 p2 = hb[(size_t)s2.x * 32 + fl];
            u32 p3 = hb[(size_t)s3.x * 32 + fl];
            float e0 = __expf(__int_as_float(s0.y) - m);
            float e1 = __expf(__int_as_float(s1.y) - m);
            float e2 = __expf(__int_as_float(s2.y) - m);
            float e3 = __expf(__int_as_float(s3.y) - m);
            ax = fmaf(e0, bf2f((u16)(p0 & 0xffffu)), ax);
            ay = fmaf(e0, bf2f((u16)(p0 >> 16)), ay);
            ax = fmaf(e1, bf2f((u16)(p1 & 0xffffu)), ax);
            ay = fmaf(e1, bf2f((u16)(p1 >> 16)), ay);
            ax = fmaf(e2, bf2f((u16)(p2 & 0xffffu)), ax);
            ay = fmaf(e2, bf2f((u16)(p2 >> 16)), ay);
            ax = fmaf(e3, bf2f((u16)(p3 & 0xffffu)), ax);
            ay = fmaf(e3, bf2f((u16)(p3 >> 16)), ay);
        }
    }
    for (; j0 < deg; j0 += 2) {
        int j = j0 + half;
        float ex = 0.f;
        int src = 0;
        if (j < deg) {
            int2 sa = (j < CAP) ? cw[j] : ealpha(j);
            src = sa.x;
            ex = __expf(__int_as_float(sa.y) - m);
        }
        u32 pk = hb[(size_t)src * 32 + fl];
        ax = fmaf(ex, bf2f((u16)(pk & 0xffffu)), ax);
        ay = fmaf(ex, bf2f((u16)(pk >> 16)), ay);
    }
    ax += __shfl_xor(ax, 32);
    ay += __shfl_xor(ay, 32);

    if (!active) return;
    float inv = 1.0f / (ssum + 1e-16f);

    if (MODE == 0) {
        if (lane < 32) {
            float2 v = make_float2(fmaxf(ax * inv, 0.f), fmaxf(ay * inv, 0.f));
            *(float2*)&hout[(size_t)node * 64 + fl * 2] = v;
        }
    } else {
        float r0 = ax * inv, r1 = ay * inv;
        float l0 = r0 * P[P_CLSW + 4 * fl]     + r1 * P[P_CLSW + 4 * fl + 2];
        float l1 = r0 * P[P_CLSW + 4 * fl + 1] + r1 * P[P_CLSW + 4 * fl + 3];
        #pragma unroll
        for (int o = 16; o > 0; o >>= 1) {
            l0 += __shfl_xor(l0, o);
            l1 += __shfl_xor(l1, o);
        }
        if (lane == 0) {
            l0 += P[P_CLSB];
            l1 += P[P_CLSB + 1];
            if (flag[0]) {
                ((float2*)outp)[node] = make_float2(l0, l1);
            } else {
                ((u32*)outp)[node] = (u32)f2bf(l0) | ((u32)f2bf(l1) << 16);
            }
        }
    }
}

// ---------------------------------------------------------------------------
extern "C" void kernel_launch(void* const* d_in, const int* in_sizes, int n_in,
                              void* d_out, int out_size, void* d_ws, size_t ws_size,
                              hipStream_t stream)
{
    const void* x    = d_in[0];
    const int*  ei   = (const int*)d_in[1];
    const void* et   = d_in[2];
    const void* l1w  = d_in[3];
    const void* l1b  = d_in[4];
    const void* a1w  = d_in[5];
    const void* a1b  = d_in[6];
    const void* t1w  = d_in[7];
    const void* t1b  = d_in[8];
    const void* l2w  = d_in[9];
    const void* l2b  = d_in[10];
    const void* a2w  = d_in[11];
    const void* a2b  = d_in[12];
    const void* t2w  = d_in[13];
    const void* t2b  = d_in[14];
    const void* clsw = d_in[15];
    const void* clsb = d_in[16];

    const int N = in_sizes[0] / 128;
    const int E = in_sizes[2];
    const int npb = (N + NBKT - 1) / NBKT;   // nodes per bucket (196)

    char* ws = (char*)d_ws;
    size_t off = 0;
    auto A = [&](size_t bytes) -> char* {
        char* p = ws + off;
        off = (off + bytes + 255) & ~(size_t)255;
        return p;
    };
    int*   flag   = (int*)A(256);
    float* P      = (float*)A(P_TOT * 4);
    u32*   h1b    = (u32*)A((size_t)N * 32 * 4);   // bf16-packed h1; reused as h2
    float* si1    = (float*)A((size_t)N * 4);
    float* sj1    = (float*)A((size_t)N * 4);
    float* si2    = (float*)A((size_t)N * 4);
    float* sj2    = (float*)A((size_t)N * 4);
    int*   cur8   = (int*)A(((size_t)SH * NBKT + 64) * 4);  // + ovfcnt
    int*   ovfcnt = cur8 + SH * NBKT;
    int4*  ovf    = (int4*)A((size_t)OVFCAP * 16);
    int*   bscan  = (int*)A((size_t)NBKT * 4);
    int*   offs   = (int*)A((size_t)(N + 1) * 4);
    int2*  csr2   = (int2*)A((size_t)E * 8);
    char*  unionr = A((size_t)SH * NBKT * SCAP * 8 < (size_t)N * 64 * 4
                      ? (size_t)N * 64 * 4 : (size_t)SH * NBKT * SCAP * 8);
    int2*  staging = (int2*)unionr;          // stage/bin phase
    float* hag     = (float*)unionr;         // agg0 output (after bin)
    (void)ws_size; (void)n_in; (void)out_size;

    hipMemsetAsync(cur8, 0, ((size_t)SH * NBKT + 64) * 4, stream);

    detect_dtype<<<1, 256, 0, stream>>>((const u32*)x, 4096, flag);

    prep_params<<<32, 256, 0, stream>>>(l1w, l1b, a1w, a1b, t1w, t1b,
                                        l2w, l2b, a2w, a2b, t2w, t2b,
                                        clsw, clsb, flag, P);

    node_gemm<128, true><<<(N + 63) / 64, 256, 0, stream>>>(
        x, P, P_W1, P_B1, P_A1W, flag, h1b, si1, sj1, N);

    stage_edges<<<(E + 255) / 256, 256, 0, stream>>>(
        ei, et, flag, staging, cur8, ovfcnt, ovf, E, npb);

    bucket_scan<<<1, 512, 0, stream>>>(cur8, ovfcnt, ovf, bscan, offs, N);

    bin_edges<<<NBKT, 256, 0, stream>>>(
        staging, cur8, ovfcnt, ovf, bscan, offs, csr2, N, npb);

    aggregate<0><<<(N + 3) / 4, 256, 0, stream>>>(
        offs, csr2, h1b, si1, sj1, P, P_T1W, P_T1B, P_A1W + 128, P_A1B,
        hag, nullptr, flag, N);

    node_gemm<64, false><<<(N + 63) / 64, 256, 0, stream>>>(
        hag, P, P_W2, P_B2, P_A2W, flag, h1b, si2, sj2, N);

    aggregate<1><<<(N + 3) / 4, 256, 0, stream>>>(
        offs, csr2, h1b, si2, sj2, P, P_T2W, P_T2B, P_A2W + 128, P_A2B,
        nullptr, d_out, flag, N);
}